// Round 10
// baseline (2637.643 us; speedup 1.0000x reference)
//
#include <hip/hip_runtime.h>
#include <math.h>

// MultiViewAggregation — round 10.
// A: PBR MLP split 2-threads-per-instance (wave-uniform half -> AS4 s_load
//    preserved); 65-stride LDS exchange; ~96 live floats -> higher occupancy.
// B1/B2: round-9 LDS-staged-weight kernels unchanged.

#define NPIX 16384

__device__ __forceinline__ float elu_f(float x){ return x > 0.f ? x : (__expf(x) - 1.f); }
__device__ __forceinline__ float gelu_f(float x){ return 0.5f*x*(1.f + erff(x*0.70710678118654752f)); }

// ===================== Kernel A =====================
#define NTA 384
#define NBA (NPIX/2)

typedef float v4 __attribute__((ext_vector_type(4)));
#define AS4Q __attribute__((address_space(4)))
typedef const AS4Q v4*    cf4p;
typedef const AS4Q float* cf1p;

__device__ __forceinline__ v4 elu4(v4 a){
  v4 r; r.x = elu_f(a.x); r.y = elu_f(a.y); r.z = elu_f(a.z); r.w = elu_f(a.w); return r;
}

#define FMA4A(A, S, WV) { v4 _w = (WV); \
  A.x = fmaf((S), _w.x, A.x); A.y = fmaf((S), _w.y, A.y); \
  A.z = fmaf((S), _w.z, A.z); A.w = fmaf((S), _w.w, A.w); }

// accumulate quad Sq covering weight k-rows [base .. base+3], v4 col cq, stride LD v4
#define AK4W(A, Sq, W, base, LD) \
  FMA4A(A, (Sq).x, W[(base)*(LD)+(_cq)]) \
  FMA4A(A, (Sq).y, W[(base+1)*(LD)+(_cq)]) \
  FMA4A(A, (Sq).z, W[(base+2)*(LD)+(_cq)]) \
  FMA4A(A, (Sq).w, W[(base+3)*(LD)+(_cq)])

// accumulate 8 quads S0..S7 covering k-rows rb..rb+31
#define AK8(A, S, W, rb, LD) \
  AK4W(A, S##0, W, (rb)+ 0, LD) AK4W(A, S##1, W, (rb)+ 4, LD) \
  AK4W(A, S##2, W, (rb)+ 8, LD) AK4W(A, S##3, W, (rb)+12, LD) \
  AK4W(A, S##4, W, (rb)+16, LD) AK4W(A, S##5, W, (rb)+20, LD) \
  AK4W(A, S##6, W, (rb)+24, LD) AK4W(A, S##7, W, (rb)+28, LD)

// one output quad of 64-wide layer: own S-half (rows YR..) + partner P (rows PR..)
#define COLH64(A, S, W, B4, cb) { const int _cq = H8+(cb); A = B4[_cq]; \
  AK8(A, S, W, YR, 16) AK8(A, P, W, PR, 16) }

#define LAYERH64(D, S, W, B4) { v4 _a; \
  COLH64(_a, S, W, B4, 0) D##0 = elu4(_a); \
  COLH64(_a, S, W, B4, 1) D##1 = elu4(_a); \
  COLH64(_a, S, W, B4, 2) D##2 = elu4(_a); \
  COLH64(_a, S, W, B4, 3) D##3 = elu4(_a); \
  COLH64(_a, S, W, B4, 4) D##4 = elu4(_a); \
  COLH64(_a, S, W, B4, 5) D##5 = elu4(_a); \
  COLH64(_a, S, W, B4, 6) D##6 = elu4(_a); \
  COLH64(_a, S, W, B4, 7) D##7 = elu4(_a); }

// one output quad of the 64->32 layer (stride 8 v4)
#define COLH32(A, S, W, B4, cb) { const int _cq = H4+(cb); A = B4[_cq]; \
  AK8(A, S, W, YR, 8) AK8(A, P, W, PR, 8) }

// layer1 col quad (7 -> own 32 cols)
#define COLH1(A, cb) { const int _cq = H8+(cb); A = B1v[_cq]; \
  FMA4A(A, xl0, W1v[0*16+_cq]) FMA4A(A, xl1, W1v[1*16+_cq]) \
  FMA4A(A, xl2, W1v[2*16+_cq]) FMA4A(A, xl3, W1v[3*16+_cq]) \
  FMA4A(A, xl4, W1v[4*16+_cq]) FMA4A(A, xl5, W1v[5*16+_cq]) \
  FMA4A(A, xl6, W1v[6*16+_cq]) }

#define STQ(p, o, A) { (p)[(o)]=A.x; (p)[(o)+1]=A.y; (p)[(o)+2]=A.z; (p)[(o)+3]=A.w; }
#define LDQ(A, p, o) { A.x=(p)[(o)]; A.y=(p)[(o)+1]; A.z=(p)[(o)+2]; A.w=(p)[(o)+3]; }

#define STEX(S) { float* _r = exch + inst*65 + YR; \
  STQ(_r,0,S##0) STQ(_r,4,S##1) STQ(_r,8,S##2) STQ(_r,12,S##3) \
  STQ(_r,16,S##4) STQ(_r,20,S##5) STQ(_r,24,S##6) STQ(_r,28,S##7) }

#define LDP() { const float* _r = exch + inst*65 + PR; \
  LDQ(P0,_r,0) LDQ(P1,_r,4) LDQ(P2,_r,8) LDQ(P3,_r,12) \
  LDQ(P4,_r,16) LDQ(P5,_r,20) LDQ(P6,_r,24) LDQ(P7,_r,28) }

__global__ __launch_bounds__(NTA)
void mva_phaseA(const float* __restrict__ view_dir, const float* __restrict__ normal,
                const float* __restrict__ DL,
                const float* __restrict__ ln_g, const float* __restrict__ ln_b,
                const float* __restrict__ w1, const float* __restrict__ b1,
                const float* __restrict__ w2, const float* __restrict__ b2,
                const float* __restrict__ w3, const float* __restrict__ b3,
                const float* __restrict__ w4, const float* __restrict__ b4,
                float* __restrict__ feat)
{
  __shared__ float exch[192*65];            // 49.9 KB; fbuf aliases head
  const int t    = threadIdx.x;
  const int h    = t / 192;                 // wave-uniform (waves 0-2: 0, 3-5: 1)
  const int inst = t - h*192;               // (pxv, sg)
  const int pxv  = inst & 15;               // px_l(1)|view(3)
  const int sg   = inst >> 4;               // 0..11
  const int px   = blockIdx.x*2 + (pxv >> 3);
  const int view = pxv & 7;
  const int H8 = h*8, H4 = h*4, YR = h*32, PR = 32 - h*32;

  cf4p W1v = (cf4p)(unsigned long long)w1;
  cf4p B1v = (cf4p)(unsigned long long)b1;
  cf4p W2v = (cf4p)(unsigned long long)w2;
  cf4p B2v = (cf4p)(unsigned long long)b2;
  cf4p W3v = (cf4p)(unsigned long long)w3;
  cf4p B3v = (cf4p)(unsigned long long)b3;
  cf4p W4v = (cf4p)(unsigned long long)w4;
  cf4p B4v = (cf4p)(unsigned long long)b4;
  cf1p LG  = (cf1p)(unsigned long long)ln_g;
  cf1p LB  = (cf1p)(unsigned long long)ln_b;

  // ---- inputs + 7-wide LN (both halves duplicate: trivial) ----
  const float nm0 = normal[px*3+0], nm1 = normal[px*3+1], nm2 = normal[px*3+2];
  const float* vd = view_dir + (px*8 + view)*3;
  const float vd0 = vd[0], vd1 = vd[1], vd2 = vd[2];
  const float* dl = DL + px*84 + sg*7;
  const float d0=dl[0], d1=dl[1], d2=dl[2], d3=dl[3], d4=dl[4], d5=dl[5], d6=dl[6];

  const float DLdotN = d0*nm0 + d1*nm1 + d2*nm2;
  const float hvv    = (d0*vd0 + d1*vd1 + d2*vd2 + 1.f)*0.5f;
  const float fres   = exp2f((-5.55472f*hvv - 6.98316f)*hvv);
  const float VdotN  = vd0*nm0 + vd1*nm1 + vd2*nm2;

  const float x0 = DLdotN, x1 = d3, x2 = d4, x3 = d5, x4 = d6, x5 = fres, x6 = VdotN;
  const float m  = (x0+x1+x2+x3+x4+x5+x6)*(1.f/7.f);
  float q, var = 0.f;
  q = x0-m; var += q*q; q = x1-m; var += q*q; q = x2-m; var += q*q;
  q = x3-m; var += q*q; q = x4-m; var += q*q; q = x5-m; var += q*q;
  q = x6-m; var += q*q;
  const float rs = rsqrtf(var*(1.f/7.f) + 1e-5f);
  const float xl0 = (x0-m)*rs*LG[0] + LB[0];
  const float xl1 = (x1-m)*rs*LG[1] + LB[1];
  const float xl2 = (x2-m)*rs*LG[2] + LB[2];
  const float xl3 = (x3-m)*rs*LG[3] + LB[3];
  const float xl4 = (x4-m)*rs*LG[4] + LB[4];
  const float xl5 = (x5-m)*rs*LG[5] + LB[5];
  const float xl6 = (x6-m)*rs*LG[6] + LB[6];

  v4 Y0,Y1,Y2,Y3,Y4,Y5,Y6,Y7;       // own half activations
  v4 P0,P1,P2,P3,P4,P5,P6,P7;       // partner half
  v4 Z0,Z1,Z2,Z3,Z4,Z5,Z6,Z7;       // next-layer own half

  // ---- layer 1: 7 -> own 32 (elu) ----
  { v4 _a;
    COLH1(_a, 0) Y0 = elu4(_a);
    COLH1(_a, 1) Y1 = elu4(_a);
    COLH1(_a, 2) Y2 = elu4(_a);
    COLH1(_a, 3) Y3 = elu4(_a);
    COLH1(_a, 4) Y4 = elu4(_a);
    COLH1(_a, 5) Y5 = elu4(_a);
    COLH1(_a, 6) Y6 = elu4(_a);
    COLH1(_a, 7) Y7 = elu4(_a);
  }
  STEX(Y) __syncthreads();
  LDP()
  // ---- layer 2 ----
  LAYERH64(Z, Y, W2v, B2v)
  __syncthreads();                   // all y1 reads done
  STEX(Z) __syncthreads();
  LDP()
  // ---- layer 3 ----
  LAYERH64(Y, Z, W3v, B3v)
  __syncthreads();
  STEX(Y) __syncthreads();
  LDP()
  // ---- layer 4: 64 -> own 16 ----
  v4 F0,F1,F2,F3;
  { v4 _a;
    COLH32(_a, Y, W4v, B4v, 0) F0 = _a;
    COLH32(_a, Y, W4v, B4v, 1) F1 = _a;
    COLH32(_a, Y, W4v, B4v, 2) F2 = _a;
    COLH32(_a, Y, W4v, B4v, 3) F3 = _a;
  }
  __syncthreads();                   // exch dead -> fbuf aliases

  { float* fr = exch + inst*33 + h*16;    // fbuf[192][33]
    STQ(fr,0,F0) STQ(fr,4,F1) STQ(fr,8,F2) STQ(fr,12,F3)
  }
  __syncthreads();

  // reduce 12 sg -> feat (512 floats per block: 2px x 8v x 32c)
  for (int u = t; u < 512; u += NTA){
    const int pv = u >> 5, c = u & 31;
    float s = 0.f;
    #pragma unroll
    for (int g = 0; g < 12; ++g) s += exch[(g*16 + pv)*33 + c];
    feat[(size_t)blockIdx.x*512 + u] = s;
  }
}

// ===================== Shared B machinery (round-9) =====================
#define NTB 512

__device__ __forceinline__ void fma4(float4& a, float s, const float4 w){
  a.x = fmaf(s, w.x, a.x); a.y = fmaf(s, w.y, a.y);
  a.z = fmaf(s, w.z, a.z); a.w = fmaf(s, w.w, a.w);
}

template<int KK, int CC, int LDWG>
__device__ __forceinline__ void stageW(const float* __restrict__ Wg, int c4off,
                                       float* __restrict__ wbuf, int t)
{
  constexpr int C4 = CC/4;
  constexpr int N4 = KK*C4;
  const float4* __restrict__ s = (const float4*)Wg;
  float4* d = (float4*)wbuf;
  for (int i = t; i < N4; i += NTB){
    const int k = i / C4, c4 = i - k*C4;
    d[i] = s[k*(LDWG/4) + c4off + c4];
  }
}

__device__ __forceinline__ void ln32s(const float* __restrict__ in, int Si,
                                      float* __restrict__ out, int So,
                                      const float* __restrict__ g, const float* __restrict__ b,
                                      int t)
{
  if (t < 256){
    const int r = t >> 3, l8 = t & 7;
    const float* row = in + r*Si;
    float vals[12]; int cols[12];
    float s1 = 0.f, s2 = 0.f;
    #pragma unroll
    for (int i = 0; i < 12; ++i){
      int c = l8 + 8*i + 8*(r & 7); if (c >= 96) c -= 96;
      float a = row[c];
      cols[i] = c; vals[i] = a; s1 += a; s2 += a*a;
    }
    s1 += __shfl_xor(s1, 1); s2 += __shfl_xor(s2, 1);
    s1 += __shfl_xor(s1, 2); s2 += __shfl_xor(s2, 2);
    s1 += __shfl_xor(s1, 4); s2 += __shfl_xor(s2, 4);
    float mean = s1*(1.f/96.f);
    float var  = s2*(1.f/96.f) - mean*mean;
    float rsd = rsqrtf(var + 1e-5f);
    float* orow = out + r*So;
    #pragma unroll
    for (int i = 0; i < 12; ++i){
      int c = cols[i];
      orow[c] = (vals[i]-mean)*rsd*g[c] + b[c];
    }
  }
}

template<int K, int C, int LDW, bool GELU, bool HASB, bool RES, bool ACC>
__device__ __forceinline__ void mmR32(const float* __restrict__ inb, int S,
                                      const float* __restrict__ Wl, const float* __restrict__ bg,
                                      float* __restrict__ outb, int So,
                                      const float* __restrict__ residb, int Sr, int t)
{
  constexpr int C4 = C/4;
  const float4* __restrict__ W4 = (const float4*)Wl;
  for (int gi = t; gi < C4*16; gi += NTB){
    const int rp = gi & 15, c4 = gi >> 4;
    const float2* x0 = (const float2*)(inb + (2*rp)*S);
    const float2* x1 = (const float2*)(inb + (2*rp+1)*S);
    float4 a0 = HASB ? ((const float4*)bg)[c4] : make_float4(0.f,0.f,0.f,0.f);
    float4 a1 = a0;
    #pragma unroll 8
    for (int k2 = 0; k2 < K/2; ++k2){
      float2 xa = x0[k2], xb = x1[k2];
      float4 wA = W4[(2*k2)*(LDW/4) + c4];
      float4 wB = W4[(2*k2+1)*(LDW/4) + c4];
      fma4(a0, xa.x, wA); fma4(a0, xa.y, wB);
      fma4(a1, xb.x, wA); fma4(a1, xb.y, wB);
    }
    if (GELU){
      a0.x=gelu_f(a0.x); a0.y=gelu_f(a0.y); a0.z=gelu_f(a0.z); a0.w=gelu_f(a0.w);
      a1.x=gelu_f(a1.x); a1.y=gelu_f(a1.y); a1.z=gelu_f(a1.z); a1.w=gelu_f(a1.w);
    }
    if (RES){
      const float* r0 = residb + (2*rp)*Sr + 4*c4;
      const float* r1 = residb + (2*rp+1)*Sr + 4*c4;
      a0.x += r0[0]; a0.y += r0[1]; a0.z += r0[2]; a0.w += r0[3];
      a1.x += r1[0]; a1.y += r1[1]; a1.z += r1[2]; a1.w += r1[3];
    }
    float* o0 = outb + (2*rp)*So + 4*c4;
    float* o1 = outb + (2*rp+1)*So + 4*c4;
    if (ACC){
      a0.x += o0[0]; a0.y += o0[1]; a0.z += o0[2]; a0.w += o0[3];
      a1.x += o1[0]; a1.y += o1[1]; a1.z += o1[2]; a1.w += o1[3];
    }
    o0[0]=a0.x; o0[1]=a0.y; o0[2]=a0.z; o0[3]=a0.w;
    o1[0]=a1.x; o1[1]=a1.y; o1[2]=a1.z; o1[3]=a1.w;
  }
}

// ===================== Kernel B1 (round-9, unchanged) =====================
#define NBB1 (NPIX/4)
constexpr int BXIN  = 0;
constexpr int BXCUR = 3264;
constexpr int BXLN  = 6528;
constexpr int BHID  = 9792;
constexpr int BVB   = 14080;
constexpr int BMEAN = 15296;
constexpr int BVAR  = 15424;
constexpr int BWGT  = 15552;
constexpr int BWBUF = 15584;
constexpr int B1TOT = 27872;

__global__ __launch_bounds__(NTB)
void mva_phaseB1(const float* __restrict__ rgb, const float* __restrict__ fm,
                 const float* __restrict__ proj_err, float* __restrict__ ws,
                 const float* __restrict__ tv1_ln_g, const float* __restrict__ tv1_ln_b,
                 const float* __restrict__ tv1_w,
                 const float* __restrict__ to1_w, const float* __restrict__ to1_b,
                 const float* __restrict__ n1_ln_g, const float* __restrict__ n1_ln_b,
                 const float* __restrict__ n1_w1, const float* __restrict__ n1_b1,
                 const float* __restrict__ n1_w2, const float* __restrict__ n1_b2,
                 const float* __restrict__ tv2_ln_g, const float* __restrict__ tv2_ln_b,
                 const float* __restrict__ tv2_w)
{
  __shared__ __align__(16) float smem[B1TOT];
  const int t = threadIdx.x;
  const int bpx0 = blockIdx.x*4;
  float* WB = smem + BWBUF;

  for (int u = t; u < 2048; u += NTB){
    const int r = u >> 6, k = u & 63;
    const int pl = r >> 3, v = r & 7;
    float val = (k < 3) ? rgb[((bpx0+pl)*8 + v)*3 + k]
                        : fm[(bpx0+pl)*61 + (k-3)];
    smem[BXIN + r*102 + k] = val;
  }
  for (int u = t; u < 1024; u += NTB){
    const int r = u >> 5, c = u & 31;
    smem[BXIN + r*102 + 64 + c] = ws[(size_t)blockIdx.x*1024 + u];
  }
  if (t < 32){
    float pe = proj_err[(bpx0 + (t>>3))*8 + (t&7)];
    float wraw = fmaxf(-log10f(fabsf(pe) + 1e-6f), 0.f);
    float s = wraw;
    s += __shfl_xor(s, 1); s += __shfl_xor(s, 2); s += __shfl_xor(s, 4);
    smem[BWGT + t] = wraw / (s + 1e-6f);
  }
  stageW<96,32,32>(tv1_w, 0, WB, t);
  __syncthreads();

  ln32s(smem+BXIN, 102, smem+BXLN, 102, tv1_ln_g, tv1_ln_b, t);
  __syncthreads();
  mmR32<96,32,32,false,false,false,false>(smem+BXLN, 102, WB, nullptr, smem+BVB, 38, nullptr, 0, t);
  __syncthreads();
  if (t < 128){
    const int pl = t >> 5, c = t & 31;
    const float* wn = smem + BWGT + pl*8;
    float m = 0.f;
    #pragma unroll
    for (int v = 0; v < 8; ++v) m += wn[v]*smem[BVB + (pl*8+v)*38 + c];
    float vv = 0.f;
    #pragma unroll
    for (int v = 0; v < 8; ++v){ float d = smem[BVB + (pl*8+v)*38 + c] - m; vv += wn[v]*d*d; }
    smem[BMEAN + pl*32 + c] = m;
    smem[BVAR  + pl*32 + c] = vv;
  }
  __syncthreads();
  for (int u = t; u < 3072; u += NTB){
    const int r = u & 31, c = u >> 5;
    const int pl = r >> 3;
    float val = (c < 32) ? smem[BVB + r*38 + c]
              : (c < 64) ? smem[BMEAN + pl*32 + (c-32)]
                         : smem[BVAR + pl*32 + (c-64)];
    smem[BXLN + r*102 + c] = val;
  }
  stageW<96,96,96>(to1_w, 0, WB, t);
  __syncthreads();
  mmR32<96,96,96,false,true,true,false>(smem+BXLN, 102, WB, to1_b, smem+BXCUR, 102, smem+BXIN, 102, t);
  __syncthreads();

  ln32s(smem+BXCUR, 102, smem+BXLN, 102, n1_ln_g, n1_ln_b, t);
  __syncthreads();
  stageW<96,128,256>(n1_w1, 0, WB, t);
  __syncthreads();
  mmR32<96,128,128,true,true,false,false>(smem+BXLN, 102, WB, n1_b1, smem+BHID, 134, nullptr, 0, t);
  __syncthreads();
  stageW<128,96,96>(n1_w2, 0, WB, t);
  __syncthreads();
  mmR32<128,96,96,false,false,false,false>(smem+BHID, 134, WB, nullptr, smem+BXCUR, 102, nullptr, 0, t);
  __syncthreads();
  stageW<96,128,256>(n1_w1, 32, WB, t);
  __syncthreads();
  mmR32<96,128,128,true,true,false,false>(smem+BXLN, 102, WB, n1_b1 + 128, smem+BHID, 134, nullptr, 0, t);
  __syncthreads();
  stageW<128,96,96>(n1_w2 + 128*96, 0, WB, t);
  __syncthreads();
  mmR32<128,96,96,false,true,true,true>(smem+BHID, 134, WB, n1_b2, smem+BXCUR, 102, smem+BXIN, 102, t);
  __syncthreads();

  ln32s(smem+BXCUR, 102, smem+BXLN, 102, tv2_ln_g, tv2_ln_b, t);
  stageW<96,32,32>(tv2_w, 0, WB, t);
  __syncthreads();
  mmR32<96,32,32,false,false,false,false>(smem+BXLN, 102, WB, nullptr, smem+BVB, 38, nullptr, 0, t);
  __syncthreads();
  if (t < 128){
    const int pl = t >> 5, c = t & 31;
    const float* wn = smem + BWGT + pl*8;
    float m = 0.f;
    #pragma unroll
    for (int v = 0; v < 8; ++v) m += wn[v]*smem[BVB + (pl*8+v)*38 + c];
    float vv = 0.f;
    #pragma unroll
    for (int v = 0; v < 8; ++v){ float d = smem[BVB + (pl*8+v)*38 + c] - m; vv += wn[v]*d*d; }
    smem[BMEAN + pl*32 + c] = m;
    smem[BVAR  + pl*32 + c] = vv;
  }
  __syncthreads();
  if (t < 384){
    const int pl = t / 96, c = t - pl*96;
    float val = (c < 32) ? smem[BVB + (pl*8)*38 + c]
              : (c < 64) ? smem[BMEAN + pl*32 + (c-32)]
                         : smem[BVAR + pl*32 + (c-64)];
    ws[(size_t)blockIdx.x*1024 + pl*256 + 96 + c] = val;
  }
}

// ===================== Kernel B2 (round-9, unchanged) =====================
#define NBB2 (NPIX/32)
constexpr int CXLN  = 0;
constexpr int CXIN  = 3264;
constexpr int CXS   = 6528;
constexpr int CTMP  = 9792;
constexpr int CHID  = 13056;
constexpr int CWBUF = 17344;
constexpr int B2TOT = 29632;

__global__ __launch_bounds__(NTB)
void mva_phaseB2(const float* __restrict__ rgb, const float* __restrict__ fm,
                 const float* __restrict__ ws,
                 const float* __restrict__ to2_w, const float* __restrict__ to2_b,
                 const float* __restrict__ n2_ln_g, const float* __restrict__ n2_ln_b,
                 const float* __restrict__ n2_w1, const float* __restrict__ n2_b1,
                 const float* __restrict__ n2_w2, const float* __restrict__ n2_b2,
                 const float* __restrict__ brdf_ln_g, const float* __restrict__ brdf_ln_b,
                 const float* __restrict__ brdf_w1, const float* __restrict__ brdf_b1,
                 const float* __restrict__ brdf_w2, const float* __restrict__ brdf_b2,
                 float* __restrict__ out)
{
  __shared__ __align__(16) float smem[B2TOT];
  const int t = threadIdx.x;
  const int bpx0 = blockIdx.x*32;
  float* WB = smem + CWBUF;

  for (int u = t; u < 3072; u += NTB){
    const int r = u / 96, c = u - r*96;
    const int px = bpx0 + r;
    const size_t ab = ((size_t)(px >> 1))*512 + (size_t)(px & 1)*256;
    smem[CXLN + r*102 + c] = ws[ab + 96 + c];
    float xv = (c < 3)  ? rgb[((size_t)px*8)*3 + c]
             : (c < 64) ? fm[(size_t)px*61 + (c-3)]
                        : ws[ab + (c-64)];
    smem[CXIN + r*102 + c] = xv;
  }
  stageW<96,96,96>(to2_w, 0, WB, t);
  __syncthreads();

  mmR32<96,96,96,false,true,true,false>(smem+CXLN, 102, WB, to2_b, smem+CXS, 102, smem+CXIN, 102, t);
  __syncthreads();

  ln32s(smem+CXS, 102, smem+CXLN, 102, n2_ln_g, n2_ln_b, t);
  __syncthreads();
  stageW<96,128,256>(n2_w1, 0, WB, t);
  __syncthreads();
  mmR32<96,128,128,true,true,false,false>(smem+CXLN, 102, WB, n2_b1, smem+CHID, 134, nullptr, 0, t);
  __syncthreads();
  stageW<128,96,96>(n2_w2, 0, WB, t);
  __syncthreads();
  mmR32<128,96,96,false,false,false,false>(smem+CHID, 134, WB, nullptr, smem+CTMP, 102, nullptr, 0, t);
  __syncthreads();
  stageW<96,128,256>(n2_w1, 32, WB, t);
  __syncthreads();
  mmR32<96,128,128,true,true,false,false>(smem+CXLN, 102, WB, n2_b1 + 128, smem+CHID, 134, nullptr, 0, t);
  __syncthreads();
  stageW<128,96,96>(n2_w2 + 128*96, 0, WB, t);
  __syncthreads();
  mmR32<128,96,96,false,true,true,true>(smem+CHID, 134, WB, n2_b2, smem+CTMP, 102, smem+CXIN, 102, t);
  __syncthreads();

  ln32s(smem+CTMP, 102, smem+CXLN, 102, brdf_ln_g, brdf_ln_b, t);
  __syncthreads();
  stageW<96,128,128>(brdf_w1, 0, WB, t);
  __syncthreads();
  mmR32<96,128,128,true,true,false,false>(smem+CXLN, 102, WB, brdf_b1, smem+CHID, 134, nullptr, 0, t);
  __syncthreads();
  float* outp = out + (size_t)bpx0*128;
  stageW<128,64,128>(brdf_w2, 0, WB, t);
  __syncthreads();
  mmR32<128,64,64,false,true,false,false>(smem+CHID, 134, WB, brdf_b2, outp, 128, nullptr, 0, t);
  __syncthreads();
  stageW<128,64,128>(brdf_w2, 16, WB, t);
  __syncthreads();
  mmR32<128,64,64,false,true,false,false>(smem+CHID, 134, WB, brdf_b2 + 64, outp + 64, 128, nullptr, 0, t);
}

extern "C" void kernel_launch(void* const* d_in, const int* in_sizes, int n_in,
                              void* d_out, int out_size, void* d_ws, size_t ws_size,
                              hipStream_t stream)
{
  (void)in_sizes; (void)n_in; (void)ws_size; (void)out_size;
  int i = 0;
  const float* rgb      = (const float*)d_in[i++];
  const float* fm       = (const float*)d_in[i++];
  const float* view_dir = (const float*)d_in[i++];
  const float* proj_err = (const float*)d_in[i++];
  const float* normal   = (const float*)d_in[i++];
  const float* DL       = (const float*)d_in[i++];
  const float* pbr_ln_g = (const float*)d_in[i++];
  const float* pbr_ln_b = (const float*)d_in[i++];
  const float* pbr_w1   = (const float*)d_in[i++];
  const float* pbr_b1   = (const float*)d_in[i++];
  const float* pbr_w2   = (const float*)d_in[i++];
  const float* pbr_b2   = (const float*)d_in[i++];
  const float* pbr_w3   = (const float*)d_in[i++];
  const float* pbr_b3   = (const float*)d_in[i++];
  const float* pbr_w4   = (const float*)d_in[i++];
  const float* pbr_b4   = (const float*)d_in[i++];
  const float* tv1_ln_g = (const float*)d_in[i++];
  const float* tv1_ln_b = (const float*)d_in[i++];
  const float* tv1_w    = (const float*)d_in[i++];
  const float* to1_w    = (const float*)d_in[i++];
  const float* to1_b    = (const float*)d_in[i++];
  const float* n1_ln_g  = (const float*)d_in[i++];
  const float* n1_ln_b  = (const float*)d_in[i++];
  const float* n1_w1    = (const float*)d_in[i++];
  const float* n1_b1    = (const float*)d_in[i++];
  const float* n1_w2    = (const float*)d_in[i++];
  const float* n1_b2    = (const float*)d_in[i++];
  const float* tv2_ln_g = (const float*)d_in[i++];
  const float* tv2_ln_b = (const float*)d_in[i++];
  const float* tv2_w    = (const float*)d_in[i++];
  const float* to2_w    = (const float*)d_in[i++];
  const float* to2_b    = (const float*)d_in[i++];
  const float* n2_ln_g  = (const float*)d_in[i++];
  const float* n2_ln_b  = (const float*)d_in[i++];
  const float* n2_w1    = (const float*)d_in[i++];
  const float* n2_b1    = (const float*)d_in[i++];
  const float* n2_w2    = (const float*)d_in[i++];
  const float* n2_b2    = (const float*)d_in[i++];
  const float* brdf_ln_g= (const float*)d_in[i++];
  const float* brdf_ln_b= (const float*)d_in[i++];
  const float* brdf_w1  = (const float*)d_in[i++];
  const float* brdf_b1  = (const float*)d_in[i++];
  const float* brdf_w2  = (const float*)d_in[i++];
  const float* brdf_b2  = (const float*)d_in[i++];

  float* ws = (float*)d_ws;

  mva_phaseA<<<dim3(NBA), dim3(NTA), 0, stream>>>(
      view_dir, normal, DL, pbr_ln_g, pbr_ln_b,
      pbr_w1, pbr_b1, pbr_w2, pbr_b2, pbr_w3, pbr_b3, pbr_w4, pbr_b4, ws);

  mva_phaseB1<<<dim3(NBB1), dim3(NTB), 0, stream>>>(
      rgb, fm, proj_err, ws,
      tv1_ln_g, tv1_ln_b, tv1_w, to1_w, to1_b,
      n1_ln_g, n1_ln_b, n1_w1, n1_b1, n1_w2, n1_b2,
      tv2_ln_g, tv2_ln_b, tv2_w);

  mva_phaseB2<<<dim3(NBB2), dim3(NTB), 0, stream>>>(
      rgb, fm, ws,
      to2_w, to2_b,
      n2_ln_g, n2_ln_b, n2_w1, n2_b1, n2_w2, n2_b2,
      brdf_ln_g, brdf_ln_b, brdf_w1, brdf_b1, brdf_w2, brdf_b2,
      (float*)d_out);
}

// Round 11
// 1553.843 us; speedup vs baseline: 1.6975x; 1.6975x over previous
//
#include <hip/hip_runtime.h>
#include <math.h>

// MultiViewAggregation — round 11.
// A: round-9 structure (AS4 s_load weights, named v4 regs) + PRIVATE LDS park:
//    each 64->64 layer computed in column halves; half A parked in the thread's
//    own LDS row (no barriers, same-wave DS ordering), halving activation regs.
// B1/B2: round-9 LDS-staged-weight kernels, unchanged.

#define NPIX 16384

__device__ __forceinline__ float elu_f(float x){ return x > 0.f ? x : (__expf(x) - 1.f); }
__device__ __forceinline__ float gelu_f(float x){ return 0.5f*x*(1.f + erff(x*0.70710678118654752f)); }

// ===================== Kernel A =====================
#define NTA 384
#define NBA (NPIX/4)

typedef float v4 __attribute__((ext_vector_type(4)));
#define AS4Q __attribute__((address_space(4)))
typedef const AS4Q v4*    cf4p;
typedef const AS4Q float* cf1p;

__device__ __forceinline__ v4 elu4(v4 a){
  v4 r; r.x = elu_f(a.x); r.y = elu_f(a.y); r.z = elu_f(a.z); r.w = elu_f(a.w); return r;
}

#define FMA4A(A, S, WV) { v4 _w = (WV); \
  A.x = fmaf((S), _w.x, A.x); A.y = fmaf((S), _w.y, A.y); \
  A.z = fmaf((S), _w.z, A.z); A.w = fmaf((S), _w.w, A.w); }

// accumulate 4 k-rows (quad Sq) into A; weight col-quad cq, row stride LD (v4)
#define AKQ(A, Sq, W, kb, cq, LD) \
  FMA4A(A, (Sq).x, W[(kb)*(LD)+(cq)]) \
  FMA4A(A, (Sq).y, W[((kb)+1)*(LD)+(cq)]) \
  FMA4A(A, (Sq).z, W[((kb)+2)*(LD)+(cq)]) \
  FMA4A(A, (Sq).w, W[((kb)+3)*(LD)+(cq)])

// full K=64 accumulation for one output col-quad cq
#define COLQ(A, S, W, B4, cq, LD) { A = B4[cq]; \
  AKQ(A, S##0,  W,  0, cq, LD) AKQ(A, S##1,  W,  4, cq, LD) \
  AKQ(A, S##2,  W,  8, cq, LD) AKQ(A, S##3,  W, 12, cq, LD) \
  AKQ(A, S##4,  W, 16, cq, LD) AKQ(A, S##5,  W, 20, cq, LD) \
  AKQ(A, S##6,  W, 24, cq, LD) AKQ(A, S##7,  W, 28, cq, LD) \
  AKQ(A, S##8,  W, 32, cq, LD) AKQ(A, S##9,  W, 36, cq, LD) \
  AKQ(A, S##10, W, 40, cq, LD) AKQ(A, S##11, W, 44, cq, LD) \
  AKQ(A, S##12, W, 48, cq, LD) AKQ(A, S##13, W, 52, cq, LD) \
  AKQ(A, S##14, W, 56, cq, LD) AKQ(A, S##15, W, 60, cq, LD) }

#define COLL1(A, B4, cq) { A = B4[cq]; \
  FMA4A(A, xl0, W1v[0*16+(cq)]) FMA4A(A, xl1, W1v[1*16+(cq)]) \
  FMA4A(A, xl2, W1v[2*16+(cq)]) FMA4A(A, xl3, W1v[3*16+(cq)]) \
  FMA4A(A, xl4, W1v[4*16+(cq)]) FMA4A(A, xl5, W1v[5*16+(cq)]) \
  FMA4A(A, xl6, W1v[6*16+(cq)]) }

#define PK(i, A) { *(float2*)(prow + (i)*4)     = make_float2(A.x, A.y); \
                   *(float2*)(prow + (i)*4 + 2) = make_float2(A.z, A.w); }
#define UNPK(Yn, i) { float2 _p = *(const float2*)(prow + (i)*4); \
                      float2 _q = *(const float2*)(prow + (i)*4 + 2); \
                      Yn.x = _p.x; Yn.y = _p.y; Yn.z = _q.x; Yn.w = _q.y; }

#define SHF32(A) { A.x += __shfl_xor(A.x, 32); A.y += __shfl_xor(A.y, 32); \
                   A.z += __shfl_xor(A.z, 32); A.w += __shfl_xor(A.w, 32); }

#define STQ(p, o, A) { (p)[(o)]=A.x; (p)[(o)+1]=A.y; (p)[(o)+2]=A.z; (p)[(o)+3]=A.w; }

// split 64->64 layer with elu: park cols 0..31, named cols 32..63, then merge
#define LAYER64P(W, B4) { \
  { v4 _a; \
    COLQ(_a, Y, W, B4, 0, 16) _a = elu4(_a); PK(0,_a) \
    COLQ(_a, Y, W, B4, 1, 16) _a = elu4(_a); PK(1,_a) \
    COLQ(_a, Y, W, B4, 2, 16) _a = elu4(_a); PK(2,_a) \
    COLQ(_a, Y, W, B4, 3, 16) _a = elu4(_a); PK(3,_a) \
    COLQ(_a, Y, W, B4, 4, 16) _a = elu4(_a); PK(4,_a) \
    COLQ(_a, Y, W, B4, 5, 16) _a = elu4(_a); PK(5,_a) \
    COLQ(_a, Y, W, B4, 6, 16) _a = elu4(_a); PK(6,_a) \
    COLQ(_a, Y, W, B4, 7, 16) _a = elu4(_a); PK(7,_a) \
  } \
  __builtin_amdgcn_sched_barrier(0); \
  { v4 _a; \
    COLQ(_a, Y, W, B4, 8,  16) H0 = elu4(_a); \
    COLQ(_a, Y, W, B4, 9,  16) H1 = elu4(_a); \
    COLQ(_a, Y, W, B4, 10, 16) H2 = elu4(_a); \
    COLQ(_a, Y, W, B4, 11, 16) H3 = elu4(_a); \
    COLQ(_a, Y, W, B4, 12, 16) H4 = elu4(_a); \
    COLQ(_a, Y, W, B4, 13, 16) H5 = elu4(_a); \
    COLQ(_a, Y, W, B4, 14, 16) H6 = elu4(_a); \
    COLQ(_a, Y, W, B4, 15, 16) H7 = elu4(_a); \
  } \
  __builtin_amdgcn_sched_barrier(0); \
  UNPK(Y0,0) UNPK(Y1,1) UNPK(Y2,2) UNPK(Y3,3) \
  UNPK(Y4,4) UNPK(Y5,5) UNPK(Y6,6) UNPK(Y7,7) \
  Y8 = H0; Y9 = H1; Y10 = H2; Y11 = H3; \
  Y12 = H4; Y13 = H5; Y14 = H6; Y15 = H7; }

__global__ __launch_bounds__(NTA, 3)
void mva_phaseA(const float* __restrict__ view_dir, const float* __restrict__ normal,
                const float* __restrict__ DL,
                const float* __restrict__ ln_g, const float* __restrict__ ln_b,
                const float* __restrict__ w1, const float* __restrict__ b1,
                const float* __restrict__ w2, const float* __restrict__ b2,
                const float* __restrict__ w3, const float* __restrict__ b3,
                const float* __restrict__ w4, const float* __restrict__ b4,
                float* __restrict__ feat)
{
  __shared__ __align__(16) float lds[NTA*34];   // park [384][34] = 52.2 KB; fb aliases
  const int t   = threadIdx.x;
  const int pxv = t & 31;
  const int sg  = t >> 5;
  const int px  = blockIdx.x*4 + (pxv >> 3);
  const int view = pxv & 7;
  float* prow = lds + t*34;

  cf4p W1v = (cf4p)(unsigned long long)w1;
  cf4p B1v = (cf4p)(unsigned long long)b1;
  cf4p W2v = (cf4p)(unsigned long long)w2;
  cf4p B2v = (cf4p)(unsigned long long)b2;
  cf4p W3v = (cf4p)(unsigned long long)w3;
  cf4p B3v = (cf4p)(unsigned long long)b3;
  cf4p W4v = (cf4p)(unsigned long long)w4;
  cf4p B4v = (cf4p)(unsigned long long)b4;
  cf1p LG  = (cf1p)(unsigned long long)ln_g;
  cf1p LB  = (cf1p)(unsigned long long)ln_b;

  const float nm0 = normal[px*3+0], nm1 = normal[px*3+1], nm2 = normal[px*3+2];
  const float* vd = view_dir + (px*8 + view)*3;
  const float vd0 = vd[0], vd1 = vd[1], vd2 = vd[2];
  const float* dl = DL + px*84 + sg*7;
  const float d0=dl[0], d1=dl[1], d2=dl[2], d3=dl[3], d4=dl[4], d5=dl[5], d6=dl[6];

  const float DLdotN = d0*nm0 + d1*nm1 + d2*nm2;
  const float hv     = (d0*vd0 + d1*vd1 + d2*vd2 + 1.f)*0.5f;
  const float fres   = exp2f((-5.55472f*hv - 6.98316f)*hv);
  const float VdotN  = vd0*nm0 + vd1*nm1 + vd2*nm2;

  const float x0 = DLdotN, x1 = d3, x2 = d4, x3 = d5, x4 = d6, x5 = fres, x6 = VdotN;
  const float m  = (x0+x1+x2+x3+x4+x5+x6)*(1.f/7.f);
  float q, var = 0.f;
  q = x0-m; var += q*q; q = x1-m; var += q*q; q = x2-m; var += q*q;
  q = x3-m; var += q*q; q = x4-m; var += q*q; q = x5-m; var += q*q;
  q = x6-m; var += q*q;
  const float rs = rsqrtf(var*(1.f/7.f) + 1e-5f);
  const float xl0 = (x0-m)*rs*LG[0] + LB[0];
  const float xl1 = (x1-m)*rs*LG[1] + LB[1];
  const float xl2 = (x2-m)*rs*LG[2] + LB[2];
  const float xl3 = (x3-m)*rs*LG[3] + LB[3];
  const float xl4 = (x4-m)*rs*LG[4] + LB[4];
  const float xl5 = (x5-m)*rs*LG[5] + LB[5];
  const float xl6 = (x6-m)*rs*LG[6] + LB[6];

  v4 Y0,Y1,Y2,Y3,Y4,Y5,Y6,Y7,Y8,Y9,Y10,Y11,Y12,Y13,Y14,Y15;
  v4 H0,H1,H2,H3,H4,H5,H6,H7;

  // ---- layer 1: 7 -> 64 (elu) ----
  { v4 _a;
    COLL1(_a, B1v, 0)  Y0  = elu4(_a);
    COLL1(_a, B1v, 1)  Y1  = elu4(_a);
    COLL1(_a, B1v, 2)  Y2  = elu4(_a);
    COLL1(_a, B1v, 3)  Y3  = elu4(_a);
    COLL1(_a, B1v, 4)  Y4  = elu4(_a);
    COLL1(_a, B1v, 5)  Y5  = elu4(_a);
    COLL1(_a, B1v, 6)  Y6  = elu4(_a);
    COLL1(_a, B1v, 7)  Y7  = elu4(_a);
    COLL1(_a, B1v, 8)  Y8  = elu4(_a);
    COLL1(_a, B1v, 9)  Y9  = elu4(_a);
    COLL1(_a, B1v, 10) Y10 = elu4(_a);
    COLL1(_a, B1v, 11) Y11 = elu4(_a);
    COLL1(_a, B1v, 12) Y12 = elu4(_a);
    COLL1(_a, B1v, 13) Y13 = elu4(_a);
    COLL1(_a, B1v, 14) Y14 = elu4(_a);
    COLL1(_a, B1v, 15) Y15 = elu4(_a);
  }

  // ---- layers 2, 3 (split, parked) ----
  LAYER64P(W2v, B2v)
  LAYER64P(W3v, B3v)

  // ---- layer 4: 64 -> 32, into H ----
  { v4 _a;
    COLQ(_a, Y, W4v, B4v, 0, 8) H0 = _a;
    COLQ(_a, Y, W4v, B4v, 1, 8) H1 = _a;
    COLQ(_a, Y, W4v, B4v, 2, 8) H2 = _a;
    COLQ(_a, Y, W4v, B4v, 3, 8) H3 = _a;
    COLQ(_a, Y, W4v, B4v, 4, 8) H4 = _a;
    COLQ(_a, Y, W4v, B4v, 5, 8) H5 = _a;
    COLQ(_a, Y, W4v, B4v, 6, 8) H6 = _a;
    COLQ(_a, Y, W4v, B4v, 7, 8) H7 = _a;
  }

  // ---- sg-pair reduction + cross-wave reduce (fb aliases park) ----
  SHF32(H0) SHF32(H1) SHF32(H2) SHF32(H3)
  SHF32(H4) SHF32(H5) SHF32(H6) SHF32(H7)

  __syncthreads();   // all threads past their last park read
  if ((t & 63) < 32){
    float* fr = lds + (t>>6)*1056 + pxv*33;   // fb[6][32][33]
    STQ(fr, 0,  H0) STQ(fr, 4,  H1) STQ(fr, 8,  H2) STQ(fr, 12, H3)
    STQ(fr, 16, H4) STQ(fr, 20, H5) STQ(fr, 24, H6) STQ(fr, 28, H7)
  }
  __syncthreads();

  for (int u = t; u < 1024; u += NTA){
    const int pv = u >> 5, c = u & 31;
    float s = 0.f;
    #pragma unroll
    for (int w = 0; w < 6; ++w) s += lds[w*1056 + pv*33 + c];
    feat[(size_t)blockIdx.x*1024 + u] = s;
  }
}

// ===================== Shared B machinery (round-9) =====================
#define NTB 512

__device__ __forceinline__ void fma4(float4& a, float s, const float4 w){
  a.x = fmaf(s, w.x, a.x); a.y = fmaf(s, w.y, a.y);
  a.z = fmaf(s, w.z, a.z); a.w = fmaf(s, w.w, a.w);
}

template<int KK, int CC, int LDWG>
__device__ __forceinline__ void stageW(const float* __restrict__ Wg, int c4off,
                                       float* __restrict__ wbuf, int t)
{
  constexpr int C4 = CC/4;
  constexpr int N4 = KK*C4;
  const float4* __restrict__ s = (const float4*)Wg;
  float4* d = (float4*)wbuf;
  for (int i = t; i < N4; i += NTB){
    const int k = i / C4, c4 = i - k*C4;
    d[i] = s[k*(LDWG/4) + c4off + c4];
  }
}

__device__ __forceinline__ void ln32s(const float* __restrict__ in, int Si,
                                      float* __restrict__ out, int So,
                                      const float* __restrict__ g, const float* __restrict__ b,
                                      int t)
{
  if (t < 256){
    const int r = t >> 3, l8 = t & 7;
    const float* row = in + r*Si;
    float vals[12]; int cols[12];
    float s1 = 0.f, s2 = 0.f;
    #pragma unroll
    for (int i = 0; i < 12; ++i){
      int c = l8 + 8*i + 8*(r & 7); if (c >= 96) c -= 96;
      float a = row[c];
      cols[i] = c; vals[i] = a; s1 += a; s2 += a*a;
    }
    s1 += __shfl_xor(s1, 1); s2 += __shfl_xor(s2, 1);
    s1 += __shfl_xor(s1, 2); s2 += __shfl_xor(s2, 2);
    s1 += __shfl_xor(s1, 4); s2 += __shfl_xor(s2, 4);
    float mean = s1*(1.f/96.f);
    float var  = s2*(1.f/96.f) - mean*mean;
    float rsd = rsqrtf(var + 1e-5f);
    float* orow = out + r*So;
    #pragma unroll
    for (int i = 0; i < 12; ++i){
      int c = cols[i];
      orow[c] = (vals[i]-mean)*rsd*g[c] + b[c];
    }
  }
}

template<int K, int C, int LDW, bool GELU, bool HASB, bool RES, bool ACC>
__device__ __forceinline__ void mmR32(const float* __restrict__ inb, int S,
                                      const float* __restrict__ Wl, const float* __restrict__ bg,
                                      float* __restrict__ outb, int So,
                                      const float* __restrict__ residb, int Sr, int t)
{
  constexpr int C4 = C/4;
  const float4* __restrict__ W4 = (const float4*)Wl;
  for (int gi = t; gi < C4*16; gi += NTB){
    const int rp = gi & 15, c4 = gi >> 4;
    const float2* x0 = (const float2*)(inb + (2*rp)*S);
    const float2* x1 = (const float2*)(inb + (2*rp+1)*S);
    float4 a0 = HASB ? ((const float4*)bg)[c4] : make_float4(0.f,0.f,0.f,0.f);
    float4 a1 = a0;
    #pragma unroll 8
    for (int k2 = 0; k2 < K/2; ++k2){
      float2 xa = x0[k2], xb = x1[k2];
      float4 wA = W4[(2*k2)*(LDW/4) + c4];
      float4 wB = W4[(2*k2+1)*(LDW/4) + c4];
      fma4(a0, xa.x, wA); fma4(a0, xa.y, wB);
      fma4(a1, xb.x, wA); fma4(a1, xb.y, wB);
    }
    if (GELU){
      a0.x=gelu_f(a0.x); a0.y=gelu_f(a0.y); a0.z=gelu_f(a0.z); a0.w=gelu_f(a0.w);
      a1.x=gelu_f(a1.x); a1.y=gelu_f(a1.y); a1.z=gelu_f(a1.z); a1.w=gelu_f(a1.w);
    }
    if (RES){
      const float* r0 = residb + (2*rp)*Sr + 4*c4;
      const float* r1 = residb + (2*rp+1)*Sr + 4*c4;
      a0.x += r0[0]; a0.y += r0[1]; a0.z += r0[2]; a0.w += r0[3];
      a1.x += r1[0]; a1.y += r1[1]; a1.z += r1[2]; a1.w += r1[3];
    }
    float* o0 = outb + (2*rp)*So + 4*c4;
    float* o1 = outb + (2*rp+1)*So + 4*c4;
    if (ACC){
      a0.x += o0[0]; a0.y += o0[1]; a0.z += o0[2]; a0.w += o0[3];
      a1.x += o1[0]; a1.y += o1[1]; a1.z += o1[2]; a1.w += o1[3];
    }
    o0[0]=a0.x; o0[1]=a0.y; o0[2]=a0.z; o0[3]=a0.w;
    o1[0]=a1.x; o1[1]=a1.y; o1[2]=a1.z; o1[3]=a1.w;
  }
}

// ===================== Kernel B1 (round-9, unchanged) =====================
#define NBB1 (NPIX/4)
constexpr int BXIN  = 0;
constexpr int BXCUR = 3264;
constexpr int BXLN  = 6528;
constexpr int BHID  = 9792;
constexpr int BVB   = 14080;
constexpr int BMEAN = 15296;
constexpr int BVAR  = 15424;
constexpr int BWGT  = 15552;
constexpr int BWBUF = 15584;
constexpr int B1TOT = 27872;

__global__ __launch_bounds__(NTB)
void mva_phaseB1(const float* __restrict__ rgb, const float* __restrict__ fm,
                 const float* __restrict__ proj_err, float* __restrict__ ws,
                 const float* __restrict__ tv1_ln_g, const float* __restrict__ tv1_ln_b,
                 const float* __restrict__ tv1_w,
                 const float* __restrict__ to1_w, const float* __restrict__ to1_b,
                 const float* __restrict__ n1_ln_g, const float* __restrict__ n1_ln_b,
                 const float* __restrict__ n1_w1, const float* __restrict__ n1_b1,
                 const float* __restrict__ n1_w2, const float* __restrict__ n1_b2,
                 const float* __restrict__ tv2_ln_g, const float* __restrict__ tv2_ln_b,
                 const float* __restrict__ tv2_w)
{
  __shared__ __align__(16) float smem[B1TOT];
  const int t = threadIdx.x;
  const int bpx0 = blockIdx.x*4;
  float* WB = smem + BWBUF;

  for (int u = t; u < 2048; u += NTB){
    const int r = u >> 6, k = u & 63;
    const int pl = r >> 3, v = r & 7;
    float val = (k < 3) ? rgb[((bpx0+pl)*8 + v)*3 + k]
                        : fm[(bpx0+pl)*61 + (k-3)];
    smem[BXIN + r*102 + k] = val;
  }
  for (int u = t; u < 1024; u += NTB){
    const int r = u >> 5, c = u & 31;
    smem[BXIN + r*102 + 64 + c] = ws[(size_t)blockIdx.x*1024 + u];
  }
  if (t < 32){
    float pe = proj_err[(bpx0 + (t>>3))*8 + (t&7)];
    float wraw = fmaxf(-log10f(fabsf(pe) + 1e-6f), 0.f);
    float s = wraw;
    s += __shfl_xor(s, 1); s += __shfl_xor(s, 2); s += __shfl_xor(s, 4);
    smem[BWGT + t] = wraw / (s + 1e-6f);
  }
  stageW<96,32,32>(tv1_w, 0, WB, t);
  __syncthreads();

  ln32s(smem+BXIN, 102, smem+BXLN, 102, tv1_ln_g, tv1_ln_b, t);
  __syncthreads();
  mmR32<96,32,32,false,false,false,false>(smem+BXLN, 102, WB, nullptr, smem+BVB, 38, nullptr, 0, t);
  __syncthreads();
  if (t < 128){
    const int pl = t >> 5, c = t & 31;
    const float* wn = smem + BWGT + pl*8;
    float m = 0.f;
    #pragma unroll
    for (int v = 0; v < 8; ++v) m += wn[v]*smem[BVB + (pl*8+v)*38 + c];
    float vv = 0.f;
    #pragma unroll
    for (int v = 0; v < 8; ++v){ float d = smem[BVB + (pl*8+v)*38 + c] - m; vv += wn[v]*d*d; }
    smem[BMEAN + pl*32 + c] = m;
    smem[BVAR  + pl*32 + c] = vv;
  }
  __syncthreads();
  for (int u = t; u < 3072; u += NTB){
    const int r = u & 31, c = u >> 5;
    const int pl = r >> 3;
    float val = (c < 32) ? smem[BVB + r*38 + c]
              : (c < 64) ? smem[BMEAN + pl*32 + (c-32)]
                         : smem[BVAR + pl*32 + (c-64)];
    smem[BXLN + r*102 + c] = val;
  }
  stageW<96,96,96>(to1_w, 0, WB, t);
  __syncthreads();
  mmR32<96,96,96,false,true,true,false>(smem+BXLN, 102, WB, to1_b, smem+BXCUR, 102, smem+BXIN, 102, t);
  __syncthreads();

  ln32s(smem+BXCUR, 102, smem+BXLN, 102, n1_ln_g, n1_ln_b, t);
  __syncthreads();
  stageW<96,128,256>(n1_w1, 0, WB, t);
  __syncthreads();
  mmR32<96,128,128,true,true,false,false>(smem+BXLN, 102, WB, n1_b1, smem+BHID, 134, nullptr, 0, t);
  __syncthreads();
  stageW<128,96,96>(n1_w2, 0, WB, t);
  __syncthreads();
  mmR32<128,96,96,false,false,false,false>(smem+BHID, 134, WB, nullptr, smem+BXCUR, 102, nullptr, 0, t);
  __syncthreads();
  stageW<96,128,256>(n1_w1, 32, WB, t);
  __syncthreads();
  mmR32<96,128,128,true,true,false,false>(smem+BXLN, 102, WB, n1_b1 + 128, smem+BHID, 134, nullptr, 0, t);
  __syncthreads();
  stageW<128,96,96>(n1_w2 + 128*96, 0, WB, t);
  __syncthreads();
  mmR32<128,96,96,false,true,true,true>(smem+BHID, 134, WB, n1_b2, smem+BXCUR, 102, smem+BXIN, 102, t);
  __syncthreads();

  ln32s(smem+BXCUR, 102, smem+BXLN, 102, tv2_ln_g, tv2_ln_b, t);
  stageW<96,32,32>(tv2_w, 0, WB, t);
  __syncthreads();
  mmR32<96,32,32,false,false,false,false>(smem+BXLN, 102, WB, nullptr, smem+BVB, 38, nullptr, 0, t);
  __syncthreads();
  if (t < 128){
    const int pl = t >> 5, c = t & 31;
    const float* wn = smem + BWGT + pl*8;
    float m = 0.f;
    #pragma unroll
    for (int v = 0; v < 8; ++v) m += wn[v]*smem[BVB + (pl*8+v)*38 + c];
    float vv = 0.f;
    #pragma unroll
    for (int v = 0; v < 8; ++v){ float d = smem[BVB + (pl*8+v)*38 + c] - m; vv += wn[v]*d*d; }
    smem[BMEAN + pl*32 + c] = m;
    smem[BVAR  + pl*32 + c] = vv;
  }
  __syncthreads();
  if (t < 384){
    const int pl = t / 96, c = t - pl*96;
    float val = (c < 32) ? smem[BVB + (pl*8)*38 + c]
              : (c < 64) ? smem[BMEAN + pl*32 + (c-32)]
                         : smem[BVAR + pl*32 + (c-64)];
    ws[(size_t)blockIdx.x*1024 + pl*256 + 96 + c] = val;
  }
}

// ===================== Kernel B2 (round-9, unchanged) =====================
#define NBB2 (NPIX/32)
constexpr int CXLN  = 0;
constexpr int CXIN  = 3264;
constexpr int CXS   = 6528;
constexpr int CTMP  = 9792;
constexpr int CHID  = 13056;
constexpr int CWBUF = 17344;
constexpr int B2TOT = 29632;

__global__ __launch_bounds__(NTB)
void mva_phaseB2(const float* __restrict__ rgb, const float* __restrict__ fm,
                 const float* __restrict__ ws,
                 const float* __restrict__ to2_w, const float* __restrict__ to2_b,
                 const float* __restrict__ n2_ln_g, const float* __restrict__ n2_ln_b,
                 const float* __restrict__ n2_w1, const float* __restrict__ n2_b1,
                 const float* __restrict__ n2_w2, const float* __restrict__ n2_b2,
                 const float* __restrict__ brdf_ln_g, const float* __restrict__ brdf_ln_b,
                 const float* __restrict__ brdf_w1, const float* __restrict__ brdf_b1,
                 const float* __restrict__ brdf_w2, const float* __restrict__ brdf_b2,
                 float* __restrict__ out)
{
  __shared__ __align__(16) float smem[B2TOT];
  const int t = threadIdx.x;
  const int bpx0 = blockIdx.x*32;
  float* WB = smem + CWBUF;

  for (int u = t; u < 3072; u += NTB){
    const int r = u / 96, c = u - r*96;
    const int px = bpx0 + r;
    const size_t ab = ((size_t)(px >> 2))*1024 + (size_t)(px & 3)*256;
    smem[CXLN + r*102 + c] = ws[ab + 96 + c];
    float xv = (c < 3)  ? rgb[((size_t)px*8)*3 + c]
             : (c < 64) ? fm[(size_t)px*61 + (c-3)]
                        : ws[ab + (c-64)];
    smem[CXIN + r*102 + c] = xv;
  }
  stageW<96,96,96>(to2_w, 0, WB, t);
  __syncthreads();

  mmR32<96,96,96,false,true,true,false>(smem+CXLN, 102, WB, to2_b, smem+CXS, 102, smem+CXIN, 102, t);
  __syncthreads();

  ln32s(smem+CXS, 102, smem+CXLN, 102, n2_ln_g, n2_ln_b, t);
  __syncthreads();
  stageW<96,128,256>(n2_w1, 0, WB, t);
  __syncthreads();
  mmR32<96,128,128,true,true,false,false>(smem+CXLN, 102, WB, n2_b1, smem+CHID, 134, nullptr, 0, t);
  __syncthreads();
  stageW<128,96,96>(n2_w2, 0, WB, t);
  __syncthreads();
  mmR32<128,96,96,false,false,false,false>(smem+CHID, 134, WB, nullptr, smem+CTMP, 102, nullptr, 0, t);
  __syncthreads();
  stageW<96,128,256>(n2_w1, 32, WB, t);
  __syncthreads();
  mmR32<96,128,128,true,true,false,false>(smem+CXLN, 102, WB, n2_b1 + 128, smem+CHID, 134, nullptr, 0, t);
  __syncthreads();
  stageW<128,96,96>(n2_w2 + 128*96, 0, WB, t);
  __syncthreads();
  mmR32<128,96,96,false,true,true,true>(smem+CHID, 134, WB, n2_b2, smem+CTMP, 102, smem+CXIN, 102, t);
  __syncthreads();

  ln32s(smem+CTMP, 102, smem+CXLN, 102, brdf_ln_g, brdf_ln_b, t);
  __syncthreads();
  stageW<96,128,128>(brdf_w1, 0, WB, t);
  __syncthreads();
  mmR32<96,128,128,true,true,false,false>(smem+CXLN, 102, WB, brdf_b1, smem+CHID, 134, nullptr, 0, t);
  __syncthreads();
  float* outp = out + (size_t)bpx0*128;
  stageW<128,64,128>(brdf_w2, 0, WB, t);
  __syncthreads();
  mmR32<128,64,64,false,true,false,false>(smem+CHID, 134, WB, brdf_b2, outp, 128, nullptr, 0, t);
  __syncthreads();
  stageW<128,64,128>(brdf_w2, 16, WB, t);
  __syncthreads();
  mmR32<128,64,64,false,true,false,false>(smem+CHID, 134, WB, brdf_b2 + 64, outp + 64, 128, nullptr, 0, t);
}

extern "C" void kernel_launch(void* const* d_in, const int* in_sizes, int n_in,
                              void* d_out, int out_size, void* d_ws, size_t ws_size,
                              hipStream_t stream)
{
  (void)in_sizes; (void)n_in; (void)ws_size; (void)out_size;
  int i = 0;
  const float* rgb      = (const float*)d_in[i++];
  const float* fm       = (const float*)d_in[i++];
  const float* view_dir = (const float*)d_in[i++];
  const float* proj_err = (const float*)d_in[i++];
  const float* normal   = (const float*)d_in[i++];
  const float* DL       = (const float*)d_in[i++];
  const float* pbr_ln_g = (const float*)d_in[i++];
  const float* pbr_ln_b = (const float*)d_in[i++];
  const float* pbr_w1   = (const float*)d_in[i++];
  const float* pbr_b1   = (const float*)d_in[i++];
  const float* pbr_w2   = (const float*)d_in[i++];
  const float* pbr_b2   = (const float*)d_in[i++];
  const float* pbr_w3   = (const float*)d_in[i++];
  const float* pbr_b3   = (const float*)d_in[i++];
  const float* pbr_w4   = (const float*)d_in[i++];
  const float* pbr_b4   = (const float*)d_in[i++];
  const float* tv1_ln_g = (const float*)d_in[i++];
  const float* tv1_ln_b = (const float*)d_in[i++];
  const float* tv1_w    = (const float*)d_in[i++];
  const float* to1_w    = (const float*)d_in[i++];
  const float* to1_b    = (const float*)d_in[i++];
  const float* n1_ln_g  = (const float*)d_in[i++];
  const float* n1_ln_b  = (const float*)d_in[i++];
  const float* n1_w1    = (const float*)d_in[i++];
  const float* n1_b1    = (const float*)d_in[i++];
  const float* n1_w2    = (const float*)d_in[i++];
  const float* n1_b2    = (const float*)d_in[i++];
  const float* tv2_ln_g = (const float*)d_in[i++];
  const float* tv2_ln_b = (const float*)d_in[i++];
  const float* tv2_w    = (const float*)d_in[i++];
  const float* to2_w    = (const float*)d_in[i++];
  const float* to2_b    = (const float*)d_in[i++];
  const float* n2_ln_g  = (const float*)d_in[i++];
  const float* n2_ln_b  = (const float*)d_in[i++];
  const float* n2_w1    = (const float*)d_in[i++];
  const float* n2_b1    = (const float*)d_in[i++];
  const float* n2_w2    = (const float*)d_in[i++];
  const float* n2_b2    = (const float*)d_in[i++];
  const float* brdf_ln_g= (const float*)d_in[i++];
  const float* brdf_ln_b= (const float*)d_in[i++];
  const float* brdf_w1  = (const float*)d_in[i++];
  const float* brdf_b1  = (const float*)d_in[i++];
  const float* brdf_w2  = (const float*)d_in[i++];
  const float* brdf_b2  = (const float*)d_in[i++];

  float* ws = (float*)d_ws;

  mva_phaseA<<<dim3(NBA), dim3(NTA), 0, stream>>>(
      view_dir, normal, DL, pbr_ln_g, pbr_ln_b,
      pbr_w1, pbr_b1, pbr_w2, pbr_b2, pbr_w3, pbr_b3, pbr_w4, pbr_b4, ws);

  mva_phaseB1<<<dim3(NBB1), dim3(NTB), 0, stream>>>(
      rgb, fm, proj_err, ws,
      tv1_ln_g, tv1_ln_b, tv1_w, to1_w, to1_b,
      n1_ln_g, n1_ln_b, n1_w1, n1_b1, n1_w2, n1_b2,
      tv2_ln_g, tv2_ln_b, tv2_w);

  mva_phaseB2<<<dim3(NBB2), dim3(NTB), 0, stream>>>(
      rgb, fm, ws,
      to2_w, to2_b,
      n2_ln_g, n2_ln_b, n2_w1, n2_b1, n2_w2, n2_b2,
      brdf_ln_g, brdf_ln_b, brdf_w1, brdf_b1, brdf_w2, brdf_b2,
      (float*)d_out);
}

// Round 12
// 1378.937 us; speedup vs baseline: 1.9128x; 1.1268x over previous
//
#include <hip/hip_runtime.h>
#include <math.h>

// MultiViewAggregation — round 12.
// A: row-batched MLP (B1-style): 1 px = 96 instance rows per 384-thr block;
//    activations in LDS ping-pong [96][68]; weights staged per layer in LDS;
//    unit = (row-quad, col-quad) -> FMA-bound inner loop.
// B1/B2: round-9 kernels, unchanged.

#define NPIX 16384

__device__ __forceinline__ float elu_f(float x){ return x > 0.f ? x : (__expf(x) - 1.f); }
__device__ __forceinline__ float gelu_f(float x){ return 0.5f*x*(1.f + erff(x*0.70710678118654752f)); }

__device__ __forceinline__ void fma4(float4& a, float s, const float4 w){
  a.x = fmaf(s, w.x, a.x); a.y = fmaf(s, w.y, a.y);
  a.z = fmaf(s, w.z, a.z); a.w = fmaf(s, w.w, a.w);
}
__device__ __forceinline__ float4 elu4f(float4 a){
  return make_float4(elu_f(a.x), elu_f(a.y), elu_f(a.z), elu_f(a.w));
}

// ===================== Kernel A =====================
#define NTA 384
#define NBA NPIX   // 1 pixel per block

// LDS float offsets
constexpr int AYA   = 0;        // [96][68] = 6528
constexpr int AYB   = 6528;     // [96][68] = 6528 ; F[96][34] aliases its head
constexpr int AWB   = 13056;    // 4096 max (64x64)
constexpr int AXL   = 17152;    // [96][8] = 768
constexpr int ABIAS = 17920;    // 224 (b1@0, b2@64, b3@128, b4@192)
constexpr int ATOT  = 18144;    // 72.6 KB -> 2 blocks/CU

// stage K x C weight block into wbuf [KPAD][C], zero rows >= KREAL
template<int KPAD, int C, int KREAL>
__device__ __forceinline__ void stageWA(const float* __restrict__ Wg,
                                        float* __restrict__ wbuf, int t)
{
  constexpr int C4 = C/4;
  const float4* __restrict__ s = (const float4*)Wg;
  float4* d = (float4*)wbuf;
  for (int i = t; i < KPAD*C4; i += NTA){
    const int k = i / C4, c4 = i - k*C4;
    d[i] = (k < KREAL) ? s[k*C4 + c4] : make_float4(0.f,0.f,0.f,0.f);
  }
}

// 96-row x 64-col layer: unit (rq = t>>4 in [0,24), c4 = t&15)
template<int K, int SI, bool DOELU>
__device__ __forceinline__ void mmA64(const float* __restrict__ Xin,
                                      const float* __restrict__ WB,
                                      const float* __restrict__ bias,
                                      float* __restrict__ Yout, int t)
{
  const int rq = t >> 4, c4 = t & 15;
  const float* x0 = Xin + (4*rq+0)*SI;
  const float* x1 = Xin + (4*rq+1)*SI;
  const float* x2 = Xin + (4*rq+2)*SI;
  const float* x3 = Xin + (4*rq+3)*SI;
  const float4* __restrict__ W4 = (const float4*)WB;
  const float4 b = ((const float4*)bias)[c4];
  float4 a0=b, a1=b, a2=b, a3=b;
  #pragma unroll
  for (int k2 = 0; k2 < K/2; ++k2){
    const float2 xa = *(const float2*)(x0 + 2*k2);
    const float2 xb = *(const float2*)(x1 + 2*k2);
    const float2 xc = *(const float2*)(x2 + 2*k2);
    const float2 xd = *(const float2*)(x3 + 2*k2);
    const float4 wA = W4[(2*k2)*16 + c4];
    const float4 wB = W4[(2*k2+1)*16 + c4];
    fma4(a0, xa.x, wA); fma4(a0, xa.y, wB);
    fma4(a1, xb.x, wA); fma4(a1, xb.y, wB);
    fma4(a2, xc.x, wA); fma4(a2, xc.y, wB);
    fma4(a3, xd.x, wA); fma4(a3, xd.y, wB);
  }
  if (DOELU){ a0 = elu4f(a0); a1 = elu4f(a1); a2 = elu4f(a2); a3 = elu4f(a3); }
  *(float4*)(Yout + (4*rq+0)*68 + 4*c4) = a0;
  *(float4*)(Yout + (4*rq+1)*68 + 4*c4) = a1;
  *(float4*)(Yout + (4*rq+2)*68 + 4*c4) = a2;
  *(float4*)(Yout + (4*rq+3)*68 + 4*c4) = a3;
}

// 96-row x 32-col layer (L4): unit (rq, c2 = t&15), F stride 34, no act
__device__ __forceinline__ void mmA32(const float* __restrict__ Xin,
                                      const float* __restrict__ WB,
                                      const float* __restrict__ bias,
                                      float* __restrict__ F, int t)
{
  const int rq = t >> 4, c2 = t & 15;
  const float* x0 = Xin + (4*rq+0)*68;
  const float* x1 = Xin + (4*rq+1)*68;
  const float* x2 = Xin + (4*rq+2)*68;
  const float* x3 = Xin + (4*rq+3)*68;
  const float2* __restrict__ W2 = (const float2*)WB;   // [64][16] float2
  const float2 b = ((const float2*)bias)[c2];
  float2 a0=b, a1=b, a2=b, a3=b;
  #pragma unroll
  for (int k2 = 0; k2 < 32; ++k2){
    const float2 xa = *(const float2*)(x0 + 2*k2);
    const float2 xb = *(const float2*)(x1 + 2*k2);
    const float2 xc = *(const float2*)(x2 + 2*k2);
    const float2 xd = *(const float2*)(x3 + 2*k2);
    const float2 wA = W2[(2*k2)*16 + c2];
    const float2 wB = W2[(2*k2+1)*16 + c2];
    a0.x = fmaf(xa.x, wA.x, a0.x); a0.y = fmaf(xa.x, wA.y, a0.y);
    a0.x = fmaf(xa.y, wB.x, a0.x); a0.y = fmaf(xa.y, wB.y, a0.y);
    a1.x = fmaf(xb.x, wA.x, a1.x); a1.y = fmaf(xb.x, wA.y, a1.y);
    a1.x = fmaf(xb.y, wB.x, a1.x); a1.y = fmaf(xb.y, wB.y, a1.y);
    a2.x = fmaf(xc.x, wA.x, a2.x); a2.y = fmaf(xc.x, wA.y, a2.y);
    a2.x = fmaf(xc.y, wB.x, a2.x); a2.y = fmaf(xc.y, wB.y, a2.y);
    a3.x = fmaf(xd.x, wA.x, a3.x); a3.y = fmaf(xd.x, wA.y, a3.y);
    a3.x = fmaf(xd.y, wB.x, a3.x); a3.y = fmaf(xd.y, wB.y, a3.y);
  }
  *(float2*)(F + (4*rq+0)*34 + 2*c2) = a0;
  *(float2*)(F + (4*rq+1)*34 + 2*c2) = a1;
  *(float2*)(F + (4*rq+2)*34 + 2*c2) = a2;
  *(float2*)(F + (4*rq+3)*34 + 2*c2) = a3;
}

__global__ __launch_bounds__(NTA)
void mva_phaseA(const float* __restrict__ view_dir, const float* __restrict__ normal,
                const float* __restrict__ DL,
                const float* __restrict__ ln_g, const float* __restrict__ ln_b,
                const float* __restrict__ w1, const float* __restrict__ b1,
                const float* __restrict__ w2, const float* __restrict__ b2,
                const float* __restrict__ w3, const float* __restrict__ b3,
                const float* __restrict__ w4, const float* __restrict__ b4,
                float* __restrict__ feat)
{
  __shared__ __align__(16) float smem[ATOT];
  const int t  = threadIdx.x;
  const int px = blockIdx.x;

  // ---- stage w1 (8 rows, row7=0) + biases; threads<96 build xl rows ----
  stageWA<8,64,7>(w1, smem+AWB, t);
  {
    float4* d = (float4*)(smem+ABIAS);
    if (t >= 128 && t < 144)      d[t-128]      = ((const float4*)b1)[t-128];
    else if (t >= 144 && t < 160) d[16 + t-144] = ((const float4*)b2)[t-144];
    else if (t >= 160 && t < 176) d[32 + t-160] = ((const float4*)b3)[t-160];
    else if (t >= 176 && t < 184) d[48 + t-176] = ((const float4*)b4)[t-176];
  }
  if (t < 96){
    const int r = t, sg = r >> 3, view = r & 7;
    const float nm0 = normal[px*3+0], nm1 = normal[px*3+1], nm2 = normal[px*3+2];
    const float* vd = view_dir + (px*8 + view)*3;
    const float vd0 = vd[0], vd1 = vd[1], vd2 = vd[2];
    const float* dl = DL + px*84 + sg*7;
    const float d0=dl[0], d1=dl[1], d2=dl[2], d3=dl[3], d4=dl[4], d5=dl[5], d6=dl[6];

    const float DLdotN = d0*nm0 + d1*nm1 + d2*nm2;
    const float hv     = (d0*vd0 + d1*vd1 + d2*vd2 + 1.f)*0.5f;
    const float fres   = exp2f((-5.55472f*hv - 6.98316f)*hv);
    const float VdotN  = vd0*nm0 + vd1*nm1 + vd2*nm2;

    const float x0 = DLdotN, x1 = d3, x2 = d4, x3 = d5, x4 = d6, x5 = fres, x6 = VdotN;
    const float m  = (x0+x1+x2+x3+x4+x5+x6)*(1.f/7.f);
    float q, var = 0.f;
    q = x0-m; var += q*q; q = x1-m; var += q*q; q = x2-m; var += q*q;
    q = x3-m; var += q*q; q = x4-m; var += q*q; q = x5-m; var += q*q;
    q = x6-m; var += q*q;
    const float rs = rsqrtf(var*(1.f/7.f) + 1e-5f);
    float* xl = smem + AXL + r*8;
    xl[0] = (x0-m)*rs*ln_g[0] + ln_b[0];
    xl[1] = (x1-m)*rs*ln_g[1] + ln_b[1];
    xl[2] = (x2-m)*rs*ln_g[2] + ln_b[2];
    xl[3] = (x3-m)*rs*ln_g[3] + ln_b[3];
    xl[4] = (x4-m)*rs*ln_g[4] + ln_b[4];
    xl[5] = (x5-m)*rs*ln_g[5] + ln_b[5];
    xl[6] = (x6-m)*rs*ln_g[6] + ln_b[6];
    xl[7] = 0.f;
  }
  __syncthreads();

  // L1: XL(8) -> YA
  mmA64<8,8,true>(smem+AXL, smem+AWB, smem+ABIAS+0, smem+AYA, t);
  __syncthreads();
  stageWA<64,64,64>(w2, smem+AWB, t);
  __syncthreads();
  // L2: YA -> YB
  mmA64<64,68,true>(smem+AYA, smem+AWB, smem+ABIAS+64, smem+AYB, t);
  __syncthreads();
  stageWA<64,64,64>(w3, smem+AWB, t);
  __syncthreads();
  // L3: YB -> YA
  mmA64<64,68,true>(smem+AYB, smem+AWB, smem+ABIAS+128, smem+AYA, t);
  __syncthreads();
  stageWA<64,32,64>(w4, smem+AWB, t);
  __syncthreads();
  // L4: YA -> F (aliases YB head, stride 34)
  mmA32(smem+AYA, smem+AWB, smem+ABIAS+192, smem+AYB, t);
  __syncthreads();

  // reduce 12 sg -> feat[px*256 + v*32 + c]
  if (t < 256){
    const int v = t >> 5, c = t & 31;
    float s = 0.f;
    #pragma unroll
    for (int sg = 0; sg < 12; ++sg) s += smem[AYB + (sg*8 + v)*34 + c];
    feat[(size_t)px*256 + t] = s;
  }
}

// ===================== Shared B machinery (round-9) =====================
#define NTB 512

template<int KK, int CC, int LDWG>
__device__ __forceinline__ void stageW(const float* __restrict__ Wg, int c4off,
                                       float* __restrict__ wbuf, int t)
{
  constexpr int C4 = CC/4;
  constexpr int N4 = KK*C4;
  const float4* __restrict__ s = (const float4*)Wg;
  float4* d = (float4*)wbuf;
  for (int i = t; i < N4; i += NTB){
    const int k = i / C4, c4 = i - k*C4;
    d[i] = s[k*(LDWG/4) + c4off + c4];
  }
}

__device__ __forceinline__ void ln32s(const float* __restrict__ in, int Si,
                                      float* __restrict__ out, int So,
                                      const float* __restrict__ g, const float* __restrict__ b,
                                      int t)
{
  if (t < 256){
    const int r = t >> 3, l8 = t & 7;
    const float* row = in + r*Si;
    float vals[12]; int cols[12];
    float s1 = 0.f, s2 = 0.f;
    #pragma unroll
    for (int i = 0; i < 12; ++i){
      int c = l8 + 8*i + 8*(r & 7); if (c >= 96) c -= 96;
      float a = row[c];
      cols[i] = c; vals[i] = a; s1 += a; s2 += a*a;
    }
    s1 += __shfl_xor(s1, 1); s2 += __shfl_xor(s2, 1);
    s1 += __shfl_xor(s1, 2); s2 += __shfl_xor(s2, 2);
    s1 += __shfl_xor(s1, 4); s2 += __shfl_xor(s2, 4);
    float mean = s1*(1.f/96.f);
    float var  = s2*(1.f/96.f) - mean*mean;
    float rsd = rsqrtf(var + 1e-5f);
    float* orow = out + r*So;
    #pragma unroll
    for (int i = 0; i < 12; ++i){
      int c = cols[i];
      orow[c] = (vals[i]-mean)*rsd*g[c] + b[c];
    }
  }
}

template<int K, int C, int LDW, bool GELU, bool HASB, bool RES, bool ACC>
__device__ __forceinline__ void mmR32(const float* __restrict__ inb, int S,
                                      const float* __restrict__ Wl, const float* __restrict__ bg,
                                      float* __restrict__ outb, int So,
                                      const float* __restrict__ residb, int Sr, int t)
{
  constexpr int C4 = C/4;
  const float4* __restrict__ W4 = (const float4*)Wl;
  for (int gi = t; gi < C4*16; gi += NTB){
    const int rp = gi & 15, c4 = gi >> 4;
    const float2* x0 = (const float2*)(inb + (2*rp)*S);
    const float2* x1 = (const float2*)(inb + (2*rp+1)*S);
    float4 a0 = HASB ? ((const float4*)bg)[c4] : make_float4(0.f,0.f,0.f,0.f);
    float4 a1 = a0;
    #pragma unroll 8
    for (int k2 = 0; k2 < K/2; ++k2){
      float2 xa = x0[k2], xb = x1[k2];
      float4 wA = W4[(2*k2)*(LDW/4) + c4];
      float4 wB = W4[(2*k2+1)*(LDW/4) + c4];
      fma4(a0, xa.x, wA); fma4(a0, xa.y, wB);
      fma4(a1, xb.x, wA); fma4(a1, xb.y, wB);
    }
    if (GELU){
      a0.x=gelu_f(a0.x); a0.y=gelu_f(a0.y); a0.z=gelu_f(a0.z); a0.w=gelu_f(a0.w);
      a1.x=gelu_f(a1.x); a1.y=gelu_f(a1.y); a1.z=gelu_f(a1.z); a1.w=gelu_f(a1.w);
    }
    if (RES){
      const float* r0 = residb + (2*rp)*Sr + 4*c4;
      const float* r1 = residb + (2*rp+1)*Sr + 4*c4;
      a0.x += r0[0]; a0.y += r0[1]; a0.z += r0[2]; a0.w += r0[3];
      a1.x += r1[0]; a1.y += r1[1]; a1.z += r1[2]; a1.w += r1[3];
    }
    float* o0 = outb + (2*rp)*So + 4*c4;
    float* o1 = outb + (2*rp+1)*So + 4*c4;
    if (ACC){
      a0.x += o0[0]; a0.y += o0[1]; a0.z += o0[2]; a0.w += o0[3];
      a1.x += o1[0]; a1.y += o1[1]; a1.z += o1[2]; a1.w += o1[3];
    }
    o0[0]=a0.x; o0[1]=a0.y; o0[2]=a0.z; o0[3]=a0.w;
    o1[0]=a1.x; o1[1]=a1.y; o1[2]=a1.z; o1[3]=a1.w;
  }
}

// ===================== Kernel B1 (round-9, unchanged) =====================
#define NBB1 (NPIX/4)
constexpr int BXIN  = 0;
constexpr int BXCUR = 3264;
constexpr int BXLN  = 6528;
constexpr int BHID  = 9792;
constexpr int BVB   = 14080;
constexpr int BMEAN = 15296;
constexpr int BVAR  = 15424;
constexpr int BWGT  = 15552;
constexpr int BWBUF = 15584;
constexpr int B1TOT = 27872;

__global__ __launch_bounds__(NTB)
void mva_phaseB1(const float* __restrict__ rgb, const float* __restrict__ fm,
                 const float* __restrict__ proj_err, float* __restrict__ ws,
                 const float* __restrict__ tv1_ln_g, const float* __restrict__ tv1_ln_b,
                 const float* __restrict__ tv1_w,
                 const float* __restrict__ to1_w, const float* __restrict__ to1_b,
                 const float* __restrict__ n1_ln_g, const float* __restrict__ n1_ln_b,
                 const float* __restrict__ n1_w1, const float* __restrict__ n1_b1,
                 const float* __restrict__ n1_w2, const float* __restrict__ n1_b2,
                 const float* __restrict__ tv2_ln_g, const float* __restrict__ tv2_ln_b,
                 const float* __restrict__ tv2_w)
{
  __shared__ __align__(16) float smem[B1TOT];
  const int t = threadIdx.x;
  const int bpx0 = blockIdx.x*4;
  float* WB = smem + BWBUF;

  for (int u = t; u < 2048; u += NTB){
    const int r = u >> 6, k = u & 63;
    const int pl = r >> 3, v = r & 7;
    float val = (k < 3) ? rgb[((bpx0+pl)*8 + v)*3 + k]
                        : fm[(bpx0+pl)*61 + (k-3)];
    smem[BXIN + r*102 + k] = val;
  }
  for (int u = t; u < 1024; u += NTB){
    const int r = u >> 5, c = u & 31;
    smem[BXIN + r*102 + 64 + c] = ws[(size_t)blockIdx.x*1024 + u];
  }
  if (t < 32){
    float pe = proj_err[(bpx0 + (t>>3))*8 + (t&7)];
    float wraw = fmaxf(-log10f(fabsf(pe) + 1e-6f), 0.f);
    float s = wraw;
    s += __shfl_xor(s, 1); s += __shfl_xor(s, 2); s += __shfl_xor(s, 4);
    smem[BWGT + t] = wraw / (s + 1e-6f);
  }
  stageW<96,32,32>(tv1_w, 0, WB, t);
  __syncthreads();

  ln32s(smem+BXIN, 102, smem+BXLN, 102, tv1_ln_g, tv1_ln_b, t);
  __syncthreads();
  mmR32<96,32,32,false,false,false,false>(smem+BXLN, 102, WB, nullptr, smem+BVB, 38, nullptr, 0, t);
  __syncthreads();
  if (t < 128){
    const int pl = t >> 5, c = t & 31;
    const float* wn = smem + BWGT + pl*8;
    float m = 0.f;
    #pragma unroll
    for (int v = 0; v < 8; ++v) m += wn[v]*smem[BVB + (pl*8+v)*38 + c];
    float vv = 0.f;
    #pragma unroll
    for (int v = 0; v < 8; ++v){ float d = smem[BVB + (pl*8+v)*38 + c] - m; vv += wn[v]*d*d; }
    smem[BMEAN + pl*32 + c] = m;
    smem[BVAR  + pl*32 + c] = vv;
  }
  __syncthreads();
  for (int u = t; u < 3072; u += NTB){
    const int r = u & 31, c = u >> 5;
    const int pl = r >> 3;
    float val = (c < 32) ? smem[BVB + r*38 + c]
              : (c < 64) ? smem[BMEAN + pl*32 + (c-32)]
                         : smem[BVAR + pl*32 + (c-64)];
    smem[BXLN + r*102 + c] = val;
  }
  stageW<96,96,96>(to1_w, 0, WB, t);
  __syncthreads();
  mmR32<96,96,96,false,true,true,false>(smem+BXLN, 102, WB, to1_b, smem+BXCUR, 102, smem+BXIN, 102, t);
  __syncthreads();

  ln32s(smem+BXCUR, 102, smem+BXLN, 102, n1_ln_g, n1_ln_b, t);
  __syncthreads();
  stageW<96,128,256>(n1_w1, 0, WB, t);
  __syncthreads();
  mmR32<96,128,128,true,true,false,false>(smem+BXLN, 102, WB, n1_b1, smem+BHID, 134, nullptr, 0, t);
  __syncthreads();
  stageW<128,96,96>(n1_w2, 0, WB, t);
  __syncthreads();
  mmR32<128,96,96,false,false,false,false>(smem+BHID, 134, WB, nullptr, smem+BXCUR, 102, nullptr, 0, t);
  __syncthreads();
  stageW<96,128,256>(n1_w1, 32, WB, t);
  __syncthreads();
  mmR32<96,128,128,true,true,false,false>(smem+BXLN, 102, WB, n1_b1 + 128, smem+BHID, 134, nullptr, 0, t);
  __syncthreads();
  stageW<128,96,96>(n1_w2 + 128*96, 0, WB, t);
  __syncthreads();
  mmR32<128,96,96,false,true,true,true>(smem+BHID, 134, WB, n1_b2, smem+BXCUR, 102, smem+BXIN, 102, t);
  __syncthreads();

  ln32s(smem+BXCUR, 102, smem+BXLN, 102, tv2_ln_g, tv2_ln_b, t);
  stageW<96,32,32>(tv2_w, 0, WB, t);
  __syncthreads();
  mmR32<96,32,32,false,false,false,false>(smem+BXLN, 102, WB, nullptr, smem+BVB, 38, nullptr, 0, t);
  __syncthreads();
  if (t < 128){
    const int pl = t >> 5, c = t & 31;
    const float* wn = smem + BWGT + pl*8;
    float m = 0.f;
    #pragma unroll
    for (int v = 0; v < 8; ++v) m += wn[v]*smem[BVB + (pl*8+v)*38 + c];
    float vv = 0.f;
    #pragma unroll
    for (int v = 0; v < 8; ++v){ float d = smem[BVB + (pl*8+v)*38 + c] - m; vv += wn[v]*d*d; }
    smem[BMEAN + pl*32 + c] = m;
    smem[BVAR  + pl*32 + c] = vv;
  }
  __syncthreads();
  if (t < 384){
    const int pl = t / 96, c = t - pl*96;
    float val = (c < 32) ? smem[BVB + (pl*8)*38 + c]
              : (c < 64) ? smem[BMEAN + pl*32 + (c-32)]
                         : smem[BVAR + pl*32 + (c-64)];
    ws[(size_t)blockIdx.x*1024 + pl*256 + 96 + c] = val;
  }
}

// ===================== Kernel B2 (round-9, unchanged) =====================
#define NBB2 (NPIX/32)
constexpr int CXLN  = 0;
constexpr int CXIN  = 3264;
constexpr int CXS   = 6528;
constexpr int CTMP  = 9792;
constexpr int CHID  = 13056;
constexpr int CWBUF = 17344;
constexpr int B2TOT = 29632;

__global__ __launch_bounds__(NTB)
void mva_phaseB2(const float* __restrict__ rgb, const float* __restrict__ fm,
                 const float* __restrict__ ws,
                 const float* __restrict__ to2_w, const float* __restrict__ to2_b,
                 const float* __restrict__ n2_ln_g, const float* __restrict__ n2_ln_b,
                 const float* __restrict__ n2_w1, const float* __restrict__ n2_b1,
                 const float* __restrict__ n2_w2, const float* __restrict__ n2_b2,
                 const float* __restrict__ brdf_ln_g, const float* __restrict__ brdf_ln_b,
                 const float* __restrict__ brdf_w1, const float* __restrict__ brdf_b1,
                 const float* __restrict__ brdf_w2, const float* __restrict__ brdf_b2,
                 float* __restrict__ out)
{
  __shared__ __align__(16) float smem[B2TOT];
  const int t = threadIdx.x;
  const int bpx0 = blockIdx.x*32;
  float* WB = smem + CWBUF;

  for (int u = t; u < 3072; u += NTB){
    const int r = u / 96, c = u - r*96;
    const int px = bpx0 + r;
    const size_t ab = ((size_t)(px >> 2))*1024 + (size_t)(px & 3)*256;
    smem[CXLN + r*102 + c] = ws[ab + 96 + c];
    float xv = (c < 3)  ? rgb[((size_t)px*8)*3 + c]
             : (c < 64) ? fm[(size_t)px*61 + (c-3)]
                        : ws[ab + (c-64)];
    smem[CXIN + r*102 + c] = xv;
  }
  stageW<96,96,96>(to2_w, 0, WB, t);
  __syncthreads();

  mmR32<96,96,96,false,true,true,false>(smem+CXLN, 102, WB, to2_b, smem+CXS, 102, smem+CXIN, 102, t);
  __syncthreads();

  ln32s(smem+CXS, 102, smem+CXLN, 102, n2_ln_g, n2_ln_b, t);
  __syncthreads();
  stageW<96,128,256>(n2_w1, 0, WB, t);
  __syncthreads();
  mmR32<96,128,128,true,true,false,false>(smem+CXLN, 102, WB, n2_b1, smem+CHID, 134, nullptr, 0, t);
  __syncthreads();
  stageW<128,96,96>(n2_w2, 0, WB, t);
  __syncthreads();
  mmR32<128,96,96,false,false,false,false>(smem+CHID, 134, WB, nullptr, smem+CTMP, 102, nullptr, 0, t);
  __syncthreads();
  stageW<96,128,256>(n2_w1, 32, WB, t);
  __syncthreads();
  mmR32<96,128,128,true,true,false,false>(smem+CXLN, 102, WB, n2_b1 + 128, smem+CHID, 134, nullptr, 0, t);
  __syncthreads();
  stageW<128,96,96>(n2_w2 + 128*96, 0, WB, t);
  __syncthreads();
  mmR32<128,96,96,false,true,true,true>(smem+CHID, 134, WB, n2_b2, smem+CTMP, 102, smem+CXIN, 102, t);
  __syncthreads();

  ln32s(smem+CTMP, 102, smem+CXLN, 102, brdf_ln_g, brdf_ln_b, t);
  __syncthreads();
  stageW<96,128,128>(brdf_w1, 0, WB, t);
  __syncthreads();
  mmR32<96,128,128,true,true,false,false>(smem+CXLN, 102, WB, brdf_b1, smem+CHID, 134, nullptr, 0, t);
  __syncthreads();
  float* outp = out + (size_t)bpx0*128;
  stageW<128,64,128>(brdf_w2, 0, WB, t);
  __syncthreads();
  mmR32<128,64,64,false,true,false,false>(smem+CHID, 134, WB, brdf_b2, outp, 128, nullptr, 0, t);
  __syncthreads();
  stageW<128,64,128>(brdf_w2, 16, WB, t);
  __syncthreads();
  mmR32<128,64,64,false,true,false,false>(smem+CHID, 134, WB, brdf_b2 + 64, outp + 64, 128, nullptr, 0, t);
}

extern "C" void kernel_launch(void* const* d_in, const int* in_sizes, int n_in,
                              void* d_out, int out_size, void* d_ws, size_t ws_size,
                              hipStream_t stream)
{
  (void)in_sizes; (void)n_in; (void)ws_size; (void)out_size;
  int i = 0;
  const float* rgb      = (const float*)d_in[i++];
  const float* fm       = (const float*)d_in[i++];
  const float* view_dir = (const float*)d_in[i++];
  const float* proj_err = (const float*)d_in[i++];
  const float* normal   = (const float*)d_in[i++];
  const float* DL       = (const float*)d_in[i++];
  const float* pbr_ln_g = (const float*)d_in[i++];
  const float* pbr_ln_b = (const float*)d_in[i++];
  const float* pbr_w1   = (const float*)d_in[i++];
  const float* pbr_b1   = (const float*)d_in[i++];
  const float* pbr_w2   = (const float*)d_in[i++];
  const float* pbr_b2   = (const float*)d_in[i++];
  const float* pbr_w3   = (const float*)d_in[i++];
  const float* pbr_b3   = (const float*)d_in[i++];
  const float* pbr_w4   = (const float*)d_in[i++];
  const float* pbr_b4   = (const float*)d_in[i++];
  const float* tv1_ln_g = (const float*)d_in[i++];
  const float* tv1_ln_b = (const float*)d_in[i++];
  const float* tv1_w    = (const float*)d_in[i++];
  const float* to1_w    = (const float*)d_in[i++];
  const float* to1_b    = (const float*)d_in[i++];
  const float* n1_ln_g  = (const float*)d_in[i++];
  const float* n1_ln_b  = (const float*)d_in[i++];
  const float* n1_w1    = (const float*)d_in[i++];
  const float* n1_b1    = (const float*)d_in[i++];
  const float* n1_w2    = (const float*)d_in[i++];
  const float* n1_b2    = (const float*)d_in[i++];
  const float* tv2_ln_g = (const float*)d_in[i++];
  const float* tv2_ln_b = (const float*)d_in[i++];
  const float* tv2_w    = (const float*)d_in[i++];
  const float* to2_w    = (const float*)d_in[i++];
  const float* to2_b    = (const float*)d_in[i++];
  const float* n2_ln_g  = (const float*)d_in[i++];
  const float* n2_ln_b  = (const float*)d_in[i++];
  const float* n2_w1    = (const float*)d_in[i++];
  const float* n2_b1    = (const float*)d_in[i++];
  const float* n2_w2    = (const float*)d_in[i++];
  const float* n2_b2    = (const float*)d_in[i++];
  const float* brdf_ln_g= (const float*)d_in[i++];
  const float* brdf_ln_b= (const float*)d_in[i++];
  const float* brdf_w1  = (const float*)d_in[i++];
  const float* brdf_b1  = (const float*)d_in[i++];
  const float* brdf_w2  = (const float*)d_in[i++];
  const float* brdf_b2  = (const float*)d_in[i++];

  float* ws = (float*)d_ws;

  mva_phaseA<<<dim3(NBA), dim3(NTA), 0, stream>>>(
      view_dir, normal, DL, pbr_ln_g, pbr_ln_b,
      pbr_w1, pbr_b1, pbr_w2, pbr_b2, pbr_w3, pbr_b3, pbr_w4, pbr_b4, ws);

  mva_phaseB1<<<dim3(NBB1), dim3(NTB), 0, stream>>>(
      rgb, fm, proj_err, ws,
      tv1_ln_g, tv1_ln_b, tv1_w, to1_w, to1_b,
      n1_ln_g, n1_ln_b, n1_w1, n1_b1, n1_w2, n1_b2,
      tv2_ln_g, tv2_ln_b, tv2_w);

  mva_phaseB2<<<dim3(NBB2), dim3(NTB), 0, stream>>>(
      rgb, fm, ws,
      to2_w, to2_b,
      n2_ln_g, n2_ln_b, n2_w1, n2_b1, n2_w2, n2_b2,
      brdf_ln_g, brdf_ln_b, brdf_w1, brdf_b1, brdf_w2, brdf_b2,
      (float*)d_out);
}

// Round 13
// 1127.753 us; speedup vs baseline: 2.3388x; 1.2227x over previous
//
#include <hip/hip_runtime.h>
#include <math.h>

// MultiViewAggregation — round 13.
// A: row-batched MLP, 2 px (192 rows) per 768-thr block; LDS ping-pong
//    activations; T14 weight prefetch (global->reg early, ds_write late).
// B1/B2: round-9 kernels, unchanged.

#define NPIX 16384

__device__ __forceinline__ float elu_f(float x){ return x > 0.f ? x : (__expf(x) - 1.f); }
__device__ __forceinline__ float gelu_f(float x){ return 0.5f*x*(1.f + erff(x*0.70710678118654752f)); }

__device__ __forceinline__ void fma4(float4& a, float s, const float4 w){
  a.x = fmaf(s, w.x, a.x); a.y = fmaf(s, w.y, a.y);
  a.z = fmaf(s, w.z, a.z); a.w = fmaf(s, w.w, a.w);
}
__device__ __forceinline__ float4 elu4f(float4 a){
  return make_float4(elu_f(a.x), elu_f(a.y), elu_f(a.z), elu_f(a.w));
}

// ===================== Kernel A =====================
#define NTA 768
#define NBA (NPIX/2)   // 2 px per block

// LDS float offsets
constexpr int AYA   = 0;        // [192][68] = 13056
constexpr int AYB   = 13056;    // [192][68] = 13056 ; F[192][34] aliases head
constexpr int AWB   = 26112;    // 4096 (64x64)
constexpr int AXL   = 30208;    // [192][8] = 1536
constexpr int ABIAS = 31744;    // 224 (b1@0, b2@64, b3@128, b4@192)
constexpr int ATOT  = 31968;    // 127.9 KB -> 1 block/CU (12 waves)

// 192-row x 64-col layer: unit (rq = t>>4 in [0,48), c4 = t&15)
template<int K, int SI, bool DOELU>
__device__ __forceinline__ void mmA64(const float* __restrict__ Xin,
                                      const float* __restrict__ WB,
                                      const float* __restrict__ bias,
                                      float* __restrict__ Yout, int t)
{
  const int rq = t >> 4, c4 = t & 15;
  const float* x0 = Xin + (4*rq+0)*SI;
  const float* x1 = Xin + (4*rq+1)*SI;
  const float* x2 = Xin + (4*rq+2)*SI;
  const float* x3 = Xin + (4*rq+3)*SI;
  const float4* __restrict__ W4 = (const float4*)WB;
  const float4 b = ((const float4*)bias)[c4];
  float4 a0=b, a1=b, a2=b, a3=b;
  #pragma unroll
  for (int k2 = 0; k2 < K/2; ++k2){
    const float2 xa = *(const float2*)(x0 + 2*k2);
    const float2 xb = *(const float2*)(x1 + 2*k2);
    const float2 xc = *(const float2*)(x2 + 2*k2);
    const float2 xd = *(const float2*)(x3 + 2*k2);
    const float4 wA = W4[(2*k2)*16 + c4];
    const float4 wB = W4[(2*k2+1)*16 + c4];
    fma4(a0, xa.x, wA); fma4(a0, xa.y, wB);
    fma4(a1, xb.x, wA); fma4(a1, xb.y, wB);
    fma4(a2, xc.x, wA); fma4(a2, xc.y, wB);
    fma4(a3, xd.x, wA); fma4(a3, xd.y, wB);
  }
  if (DOELU){ a0 = elu4f(a0); a1 = elu4f(a1); a2 = elu4f(a2); a3 = elu4f(a3); }
  *(float4*)(Yout + (4*rq+0)*68 + 4*c4) = a0;
  *(float4*)(Yout + (4*rq+1)*68 + 4*c4) = a1;
  *(float4*)(Yout + (4*rq+2)*68 + 4*c4) = a2;
  *(float4*)(Yout + (4*rq+3)*68 + 4*c4) = a3;
}

// 192-row x 32-col (L4): unit (rq, c2 = t&15), F stride 34, no act
__device__ __forceinline__ void mmA32(const float* __restrict__ Xin,
                                      const float* __restrict__ WB,
                                      const float* __restrict__ bias,
                                      float* __restrict__ F, int t)
{
  const int rq = t >> 4, c2 = t & 15;
  const float* x0 = Xin + (4*rq+0)*68;
  const float* x1 = Xin + (4*rq+1)*68;
  const float* x2 = Xin + (4*rq+2)*68;
  const float* x3 = Xin + (4*rq+3)*68;
  const float2* __restrict__ W2 = (const float2*)WB;   // [64][16] float2
  const float2 b = ((const float2*)bias)[c2];
  float2 a0=b, a1=b, a2=b, a3=b;
  #pragma unroll
  for (int k2 = 0; k2 < 32; ++k2){
    const float2 xa = *(const float2*)(x0 + 2*k2);
    const float2 xb = *(const float2*)(x1 + 2*k2);
    const float2 xc = *(const float2*)(x2 + 2*k2);
    const float2 xd = *(const float2*)(x3 + 2*k2);
    const float2 wA = W2[(2*k2)*16 + c2];
    const float2 wB = W2[(2*k2+1)*16 + c2];
    a0.x = fmaf(xa.x, wA.x, a0.x); a0.y = fmaf(xa.x, wA.y, a0.y);
    a0.x = fmaf(xa.y, wB.x, a0.x); a0.y = fmaf(xa.y, wB.y, a0.y);
    a1.x = fmaf(xb.x, wA.x, a1.x); a1.y = fmaf(xb.x, wA.y, a1.y);
    a1.x = fmaf(xb.y, wB.x, a1.x); a1.y = fmaf(xb.y, wB.y, a1.y);
    a2.x = fmaf(xc.x, wA.x, a2.x); a2.y = fmaf(xc.x, wA.y, a2.y);
    a2.x = fmaf(xc.y, wB.x, a2.x); a2.y = fmaf(xc.y, wB.y, a2.y);
    a3.x = fmaf(xd.x, wA.x, a3.x); a3.y = fmaf(xd.x, wA.y, a3.y);
    a3.x = fmaf(xd.y, wB.x, a3.x); a3.y = fmaf(xd.y, wB.y, a3.y);
  }
  *(float2*)(F + (4*rq+0)*34 + 2*c2) = a0;
  *(float2*)(F + (4*rq+1)*34 + 2*c2) = a1;
  *(float2*)(F + (4*rq+2)*34 + 2*c2) = a2;
  *(float2*)(F + (4*rq+3)*34 + 2*c2) = a3;
}

__global__ __launch_bounds__(NTA)
void mva_phaseA(const float* __restrict__ view_dir, const float* __restrict__ normal,
                const float* __restrict__ DL,
                const float* __restrict__ ln_g, const float* __restrict__ ln_b,
                const float* __restrict__ w1, const float* __restrict__ b1,
                const float* __restrict__ w2, const float* __restrict__ b2,
                const float* __restrict__ w3, const float* __restrict__ b3,
                const float* __restrict__ w4, const float* __restrict__ b4,
                float* __restrict__ feat)
{
  __shared__ __align__(16) float smem[ATOT];
  const int t = threadIdx.x;
  const int bpx0 = blockIdx.x*2;
  float4* WB4 = (float4*)(smem + AWB);

  // ---- prologue: stage w1 (8 rows, row7=0) + biases; threads<192 build xl ----
  {
    const float4* s = (const float4*)w1;
    for (int i = t; i < 128; i += NTA){
      const int k = i >> 4, c4 = i & 15;
      WB4[i] = (k < 7) ? s[k*16 + c4] : make_float4(0.f,0.f,0.f,0.f);
    }
    float4* d = (float4*)(smem+ABIAS);
    if (t >= 256 && t < 272)      d[t-256]      = ((const float4*)b1)[t-256];
    else if (t >= 272 && t < 288) d[16 + t-272] = ((const float4*)b2)[t-272];
    else if (t >= 288 && t < 304) d[32 + t-288] = ((const float4*)b3)[t-288];
    else if (t >= 304 && t < 312) d[48 + t-304] = ((const float4*)b4)[t-304];
  }
  if (t < 192){
    const int pl = t / 96, rr = t - pl*96;
    const int sg = rr >> 3, view = rr & 7;
    const int px = bpx0 + pl;
    const float nm0 = normal[px*3+0], nm1 = normal[px*3+1], nm2 = normal[px*3+2];
    const float* vd = view_dir + (px*8 + view)*3;
    const float vd0 = vd[0], vd1 = vd[1], vd2 = vd[2];
    const float* dl = DL + px*84 + sg*7;
    const float d0=dl[0], d1=dl[1], d2=dl[2], d3=dl[3], d4=dl[4], d5=dl[5], d6=dl[6];

    const float DLdotN = d0*nm0 + d1*nm1 + d2*nm2;
    const float hv     = (d0*vd0 + d1*vd1 + d2*vd2 + 1.f)*0.5f;
    const float fres   = exp2f((-5.55472f*hv - 6.98316f)*hv);
    const float VdotN  = vd0*nm0 + vd1*nm1 + vd2*nm2;

    const float x0 = DLdotN, x1 = d3, x2 = d4, x3 = d5, x4 = d6, x5 = fres, x6 = VdotN;
    const float m  = (x0+x1+x2+x3+x4+x5+x6)*(1.f/7.f);
    float q, var = 0.f;
    q = x0-m; var += q*q; q = x1-m; var += q*q; q = x2-m; var += q*q;
    q = x3-m; var += q*q; q = x4-m; var += q*q; q = x5-m; var += q*q;
    q = x6-m; var += q*q;
    const float rs = rsqrtf(var*(1.f/7.f) + 1e-5f);
    float* xl = smem + AXL + t*8;
    xl[0] = (x0-m)*rs*ln_g[0] + ln_b[0];
    xl[1] = (x1-m)*rs*ln_g[1] + ln_b[1];
    xl[2] = (x2-m)*rs*ln_g[2] + ln_b[2];
    xl[3] = (x3-m)*rs*ln_g[3] + ln_b[3];
    xl[4] = (x4-m)*rs*ln_g[4] + ln_b[4];
    xl[5] = (x5-m)*rs*ln_g[5] + ln_b[5];
    xl[6] = (x6-m)*rs*ln_g[6] + ln_b[6];
    xl[7] = 0.f;
  }
  __syncthreads();

  // ---- T14 prefetch w2 -> regs, then L1 (loads hide under compute) ----
  float4 p0 = ((const float4*)w2)[t];
  float4 p1 = (t < 256) ? ((const float4*)w2)[t + 768] : make_float4(0.f,0.f,0.f,0.f);
  mmA64<8,8,true>(smem+AXL, smem+AWB, smem+ABIAS+0, smem+AYA, t);
  __syncthreads();                 // all w1 reads done
  WB4[t] = p0; if (t < 256) WB4[t + 768] = p1;
  __syncthreads();                 // w2 visible

  // ---- prefetch w3, L2 ----
  p0 = ((const float4*)w3)[t];
  p1 = (t < 256) ? ((const float4*)w3)[t + 768] : make_float4(0.f,0.f,0.f,0.f);
  mmA64<64,68,true>(smem+AYA, smem+AWB, smem+ABIAS+64, smem+AYB, t);
  __syncthreads();
  WB4[t] = p0; if (t < 256) WB4[t + 768] = p1;
  __syncthreads();

  // ---- prefetch w4, L3 ----
  p0 = (t < 512) ? ((const float4*)w4)[t] : make_float4(0.f,0.f,0.f,0.f);
  mmA64<64,68,true>(smem+AYB, smem+AWB, smem+ABIAS+128, smem+AYA, t);
  __syncthreads();
  if (t < 512) WB4[t] = p0;
  __syncthreads();

  // ---- L4: YA -> F (aliases YB head, stride 34) ----
  mmA32(smem+AYA, smem+AWB, smem+ABIAS+192, smem+AYB, t);
  __syncthreads();

  // ---- reduce 12 sg -> feat[px*256 + v*32 + c] ----
  if (t < 512){
    const int pl = t >> 8, idx = t & 255;
    const int v = idx >> 5, c = idx & 31;
    float s = 0.f;
    #pragma unroll
    for (int sg = 0; sg < 12; ++sg) s += smem[AYB + (pl*96 + sg*8 + v)*34 + c];
    feat[(size_t)(bpx0 + pl)*256 + idx] = s;
  }
}

// ===================== Shared B machinery (round-9) =====================
#define NTB 512

template<int KK, int CC, int LDWG>
__device__ __forceinline__ void stageW(const float* __restrict__ Wg, int c4off,
                                       float* __restrict__ wbuf, int t)
{
  constexpr int C4 = CC/4;
  constexpr int N4 = KK*C4;
  const float4* __restrict__ s = (const float4*)Wg;
  float4* d = (float4*)wbuf;
  for (int i = t; i < N4; i += NTB){
    const int k = i / C4, c4 = i - k*C4;
    d[i] = s[k*(LDWG/4) + c4off + c4];
  }
}

__device__ __forceinline__ void ln32s(const float* __restrict__ in, int Si,
                                      float* __restrict__ out, int So,
                                      const float* __restrict__ g, const float* __restrict__ b,
                                      int t)
{
  if (t < 256){
    const int r = t >> 3, l8 = t & 7;
    const float* row = in + r*Si;
    float vals[12]; int cols[12];
    float s1 = 0.f, s2 = 0.f;
    #pragma unroll
    for (int i = 0; i < 12; ++i){
      int c = l8 + 8*i + 8*(r & 7); if (c >= 96) c -= 96;
      float a = row[c];
      cols[i] = c; vals[i] = a; s1 += a; s2 += a*a;
    }
    s1 += __shfl_xor(s1, 1); s2 += __shfl_xor(s2, 1);
    s1 += __shfl_xor(s1, 2); s2 += __shfl_xor(s2, 2);
    s1 += __shfl_xor(s1, 4); s2 += __shfl_xor(s2, 4);
    float mean = s1*(1.f/96.f);
    float var  = s2*(1.f/96.f) - mean*mean;
    float rsd = rsqrtf(var + 1e-5f);
    float* orow = out + r*So;
    #pragma unroll
    for (int i = 0; i < 12; ++i){
      int c = cols[i];
      orow[c] = (vals[i]-mean)*rsd*g[c] + b[c];
    }
  }
}

template<int K, int C, int LDW, bool GELU, bool HASB, bool RES, bool ACC>
__device__ __forceinline__ void mmR32(const float* __restrict__ inb, int S,
                                      const float* __restrict__ Wl, const float* __restrict__ bg,
                                      float* __restrict__ outb, int So,
                                      const float* __restrict__ residb, int Sr, int t)
{
  constexpr int C4 = C/4;
  const float4* __restrict__ W4 = (const float4*)Wl;
  for (int gi = t; gi < C4*16; gi += NTB){
    const int rp = gi & 15, c4 = gi >> 4;
    const float2* x0 = (const float2*)(inb + (2*rp)*S);
    const float2* x1 = (const float2*)(inb + (2*rp+1)*S);
    float4 a0 = HASB ? ((const float4*)bg)[c4] : make_float4(0.f,0.f,0.f,0.f);
    float4 a1 = a0;
    #pragma unroll 8
    for (int k2 = 0; k2 < K/2; ++k2){
      float2 xa = x0[k2], xb = x1[k2];
      float4 wA = W4[(2*k2)*(LDW/4) + c4];
      float4 wB = W4[(2*k2+1)*(LDW/4) + c4];
      fma4(a0, xa.x, wA); fma4(a0, xa.y, wB);
      fma4(a1, xb.x, wA); fma4(a1, xb.y, wB);
    }
    if (GELU){
      a0.x=gelu_f(a0.x); a0.y=gelu_f(a0.y); a0.z=gelu_f(a0.z); a0.w=gelu_f(a0.w);
      a1.x=gelu_f(a1.x); a1.y=gelu_f(a1.y); a1.z=gelu_f(a1.z); a1.w=gelu_f(a1.w);
    }
    if (RES){
      const float* r0 = residb + (2*rp)*Sr + 4*c4;
      const float* r1 = residb + (2*rp+1)*Sr + 4*c4;
      a0.x += r0[0]; a0.y += r0[1]; a0.z += r0[2]; a0.w += r0[3];
      a1.x += r1[0]; a1.y += r1[1]; a1.z += r1[2]; a1.w += r1[3];
    }
    float* o0 = outb + (2*rp)*So + 4*c4;
    float* o1 = outb + (2*rp+1)*So + 4*c4;
    if (ACC){
      a0.x += o0[0]; a0.y += o0[1]; a0.z += o0[2]; a0.w += o0[3];
      a1.x += o1[0]; a1.y += o1[1]; a1.z += o1[2]; a1.w += o1[3];
    }
    o0[0]=a0.x; o0[1]=a0.y; o0[2]=a0.z; o0[3]=a0.w;
    o1[0]=a1.x; o1[1]=a1.y; o1[2]=a1.z; o1[3]=a1.w;
  }
}

// ===================== Kernel B1 (round-9, unchanged) =====================
#define NBB1 (NPIX/4)
constexpr int BXIN  = 0;
constexpr int BXCUR = 3264;
constexpr int BXLN  = 6528;
constexpr int BHID  = 9792;
constexpr int BVB   = 14080;
constexpr int BMEAN = 15296;
constexpr int BVAR  = 15424;
constexpr int BWGT  = 15552;
constexpr int BWBUF = 15584;
constexpr int B1TOT = 27872;

__global__ __launch_bounds__(NTB)
void mva_phaseB1(const float* __restrict__ rgb, const float* __restrict__ fm,
                 const float* __restrict__ proj_err, float* __restrict__ ws,
                 const float* __restrict__ tv1_ln_g, const float* __restrict__ tv1_ln_b,
                 const float* __restrict__ tv1_w,
                 const float* __restrict__ to1_w, const float* __restrict__ to1_b,
                 const float* __restrict__ n1_ln_g, const float* __restrict__ n1_ln_b,
                 const float* __restrict__ n1_w1, const float* __restrict__ n1_b1,
                 const float* __restrict__ n1_w2, const float* __restrict__ n1_b2,
                 const float* __restrict__ tv2_ln_g, const float* __restrict__ tv2_ln_b,
                 const float* __restrict__ tv2_w)
{
  __shared__ __align__(16) float smem[B1TOT];
  const int t = threadIdx.x;
  const int bpx0 = blockIdx.x*4;
  float* WB = smem + BWBUF;

  for (int u = t; u < 2048; u += NTB){
    const int r = u >> 6, k = u & 63;
    const int pl = r >> 3, v = r & 7;
    float val = (k < 3) ? rgb[((bpx0+pl)*8 + v)*3 + k]
                        : fm[(bpx0+pl)*61 + (k-3)];
    smem[BXIN + r*102 + k] = val;
  }
  for (int u = t; u < 1024; u += NTB){
    const int r = u >> 5, c = u & 31;
    smem[BXIN + r*102 + 64 + c] = ws[(size_t)blockIdx.x*1024 + u];
  }
  if (t < 32){
    float pe = proj_err[(bpx0 + (t>>3))*8 + (t&7)];
    float wraw = fmaxf(-log10f(fabsf(pe) + 1e-6f), 0.f);
    float s = wraw;
    s += __shfl_xor(s, 1); s += __shfl_xor(s, 2); s += __shfl_xor(s, 4);
    smem[BWGT + t] = wraw / (s + 1e-6f);
  }
  stageW<96,32,32>(tv1_w, 0, WB, t);
  __syncthreads();

  ln32s(smem+BXIN, 102, smem+BXLN, 102, tv1_ln_g, tv1_ln_b, t);
  __syncthreads();
  mmR32<96,32,32,false,false,false,false>(smem+BXLN, 102, WB, nullptr, smem+BVB, 38, nullptr, 0, t);
  __syncthreads();
  if (t < 128){
    const int pl = t >> 5, c = t & 31;
    const float* wn = smem + BWGT + pl*8;
    float m = 0.f;
    #pragma unroll
    for (int v = 0; v < 8; ++v) m += wn[v]*smem[BVB + (pl*8+v)*38 + c];
    float vv = 0.f;
    #pragma unroll
    for (int v = 0; v < 8; ++v){ float d = smem[BVB + (pl*8+v)*38 + c] - m; vv += wn[v]*d*d; }
    smem[BMEAN + pl*32 + c] = m;
    smem[BVAR  + pl*32 + c] = vv;
  }
  __syncthreads();
  for (int u = t; u < 3072; u += NTB){
    const int r = u & 31, c = u >> 5;
    const int pl = r >> 3;
    float val = (c < 32) ? smem[BVB + r*38 + c]
              : (c < 64) ? smem[BMEAN + pl*32 + (c-32)]
                         : smem[BVAR + pl*32 + (c-64)];
    smem[BXLN + r*102 + c] = val;
  }
  stageW<96,96,96>(to1_w, 0, WB, t);
  __syncthreads();
  mmR32<96,96,96,false,true,true,false>(smem+BXLN, 102, WB, to1_b, smem+BXCUR, 102, smem+BXIN, 102, t);
  __syncthreads();

  ln32s(smem+BXCUR, 102, smem+BXLN, 102, n1_ln_g, n1_ln_b, t);
  __syncthreads();
  stageW<96,128,256>(n1_w1, 0, WB, t);
  __syncthreads();
  mmR32<96,128,128,true,true,false,false>(smem+BXLN, 102, WB, n1_b1, smem+BHID, 134, nullptr, 0, t);
  __syncthreads();
  stageW<128,96,96>(n1_w2, 0, WB, t);
  __syncthreads();
  mmR32<128,96,96,false,false,false,false>(smem+BHID, 134, WB, nullptr, smem+BXCUR, 102, nullptr, 0, t);
  __syncthreads();
  stageW<96,128,256>(n1_w1, 32, WB, t);
  __syncthreads();
  mmR32<96,128,128,true,true,false,false>(smem+BXLN, 102, WB, n1_b1 + 128, smem+BHID, 134, nullptr, 0, t);
  __syncthreads();
  stageW<128,96,96>(n1_w2 + 128*96, 0, WB, t);
  __syncthreads();
  mmR32<128,96,96,false,true,true,true>(smem+BHID, 134, WB, n1_b2, smem+BXCUR, 102, smem+BXIN, 102, t);
  __syncthreads();

  ln32s(smem+BXCUR, 102, smem+BXLN, 102, tv2_ln_g, tv2_ln_b, t);
  stageW<96,32,32>(tv2_w, 0, WB, t);
  __syncthreads();
  mmR32<96,32,32,false,false,false,false>(smem+BXLN, 102, WB, nullptr, smem+BVB, 38, nullptr, 0, t);
  __syncthreads();
  if (t < 128){
    const int pl = t >> 5, c = t & 31;
    const float* wn = smem + BWGT + pl*8;
    float m = 0.f;
    #pragma unroll
    for (int v = 0; v < 8; ++v) m += wn[v]*smem[BVB + (pl*8+v)*38 + c];
    float vv = 0.f;
    #pragma unroll
    for (int v = 0; v < 8; ++v){ float d = smem[BVB + (pl*8+v)*38 + c] - m; vv += wn[v]*d*d; }
    smem[BMEAN + pl*32 + c] = m;
    smem[BVAR  + pl*32 + c] = vv;
  }
  __syncthreads();
  if (t < 384){
    const int pl = t / 96, c = t - pl*96;
    float val = (c < 32) ? smem[BVB + (pl*8)*38 + c]
              : (c < 64) ? smem[BMEAN + pl*32 + (c-32)]
                         : smem[BVAR + pl*32 + (c-64)];
    ws[(size_t)blockIdx.x*1024 + pl*256 + 96 + c] = val;
  }
}

// ===================== Kernel B2 (round-9, unchanged) =====================
#define NBB2 (NPIX/32)
constexpr int CXLN  = 0;
constexpr int CXIN  = 3264;
constexpr int CXS   = 6528;
constexpr int CTMP  = 9792;
constexpr int CHID  = 13056;
constexpr int CWBUF = 17344;
constexpr int B2TOT = 29632;

__global__ __launch_bounds__(NTB)
void mva_phaseB2(const float* __restrict__ rgb, const float* __restrict__ fm,
                 const float* __restrict__ ws,
                 const float* __restrict__ to2_w, const float* __restrict__ to2_b,
                 const float* __restrict__ n2_ln_g, const float* __restrict__ n2_ln_b,
                 const float* __restrict__ n2_w1, const float* __restrict__ n2_b1,
                 const float* __restrict__ n2_w2, const float* __restrict__ n2_b2,
                 const float* __restrict__ brdf_ln_g, const float* __restrict__ brdf_ln_b,
                 const float* __restrict__ brdf_w1, const float* __restrict__ brdf_b1,
                 const float* __restrict__ brdf_w2, const float* __restrict__ brdf_b2,
                 float* __restrict__ out)
{
  __shared__ __align__(16) float smem[B2TOT];
  const int t = threadIdx.x;
  const int bpx0 = blockIdx.x*32;
  float* WB = smem + CWBUF;

  for (int u = t; u < 3072; u += NTB){
    const int r = u / 96, c = u - r*96;
    const int px = bpx0 + r;
    const size_t ab = (size_t)px*256;
    smem[CXLN + r*102 + c] = ws[ab + 96 + c];
    float xv = (c < 3)  ? rgb[((size_t)px*8)*3 + c]
             : (c < 64) ? fm[(size_t)px*61 + (c-3)]
                        : ws[ab + (c-64)];
    smem[CXIN + r*102 + c] = xv;
  }
  stageW<96,96,96>(to2_w, 0, WB, t);
  __syncthreads();

  mmR32<96,96,96,false,true,true,false>(smem+CXLN, 102, WB, to2_b, smem+CXS, 102, smem+CXIN, 102, t);
  __syncthreads();

  ln32s(smem+CXS, 102, smem+CXLN, 102, n2_ln_g, n2_ln_b, t);
  __syncthreads();
  stageW<96,128,256>(n2_w1, 0, WB, t);
  __syncthreads();
  mmR32<96,128,128,true,true,false,false>(smem+CXLN, 102, WB, n2_b1, smem+CHID, 134, nullptr, 0, t);
  __syncthreads();
  stageW<128,96,96>(n2_w2, 0, WB, t);
  __syncthreads();
  mmR32<128,96,96,false,false,false,false>(smem+CHID, 134, WB, nullptr, smem+CTMP, 102, nullptr, 0, t);
  __syncthreads();
  stageW<96,128,256>(n2_w1, 32, WB, t);
  __syncthreads();
  mmR32<96,128,128,true,true,false,false>(smem+CXLN, 102, WB, n2_b1 + 128, smem+CHID, 134, nullptr, 0, t);
  __syncthreads();
  stageW<128,96,96>(n2_w2 + 128*96, 0, WB, t);
  __syncthreads();
  mmR32<128,96,96,false,true,true,true>(smem+CHID, 134, WB, n2_b2, smem+CTMP, 102, smem+CXIN, 102, t);
  __syncthreads();

  ln32s(smem+CTMP, 102, smem+CXLN, 102, brdf_ln_g, brdf_ln_b, t);
  __syncthreads();
  stageW<96,128,128>(brdf_w1, 0, WB, t);
  __syncthreads();
  mmR32<96,128,128,true,true,false,false>(smem+CXLN, 102, WB, brdf_b1, smem+CHID, 134, nullptr, 0, t);
  __syncthreads();
  float* outp = out + (size_t)bpx0*128;
  stageW<128,64,128>(brdf_w2, 0, WB, t);
  __syncthreads();
  mmR32<128,64,64,false,true,false,false>(smem+CHID, 134, WB, brdf_b2, outp, 128, nullptr, 0, t);
  __syncthreads();
  stageW<128,64,128>(brdf_w2, 16, WB, t);
  __syncthreads();
  mmR32<128,64,64,false,true,false,false>(smem+CHID, 134, WB, brdf_b2 + 64, outp + 64, 128, nullptr, 0, t);
}

extern "C" void kernel_launch(void* const* d_in, const int* in_sizes, int n_in,
                              void* d_out, int out_size, void* d_ws, size_t ws_size,
                              hipStream_t stream)
{
  (void)in_sizes; (void)n_in; (void)ws_size; (void)out_size;
  int i = 0;
  const float* rgb      = (const float*)d_in[i++];
  const float* fm       = (const float*)d_in[i++];
  const float* view_dir = (const float*)d_in[i++];
  const float* proj_err = (const float*)d_in[i++];
  const float* normal   = (const float*)d_in[i++];
  const float* DL       = (const float*)d_in[i++];
  const float* pbr_ln_g = (const float*)d_in[i++];
  const float* pbr_ln_b = (const float*)d_in[i++];
  const float* pbr_w1   = (const float*)d_in[i++];
  const float* pbr_b1   = (const float*)d_in[i++];
  const float* pbr_w2   = (const float*)d_in[i++];
  const float* pbr_b2   = (const float*)d_in[i++];
  const float* pbr_w3   = (const float*)d_in[i++];
  const float* pbr_b3   = (const float*)d_in[i++];
  const float* pbr_w4   = (const float*)d_in[i++];
  const float* pbr_b4   = (const float*)d_in[i++];
  const float* tv1_ln_g = (const float*)d_in[i++];
  const float* tv1_ln_b = (const float*)d_in[i++];
  const float* tv1_w    = (const float*)d_in[i++];
  const float* to1_w    = (const float*)d_in[i++];
  const float* to1_b    = (const float*)d_in[i++];
  const float* n1_ln_g  = (const float*)d_in[i++];
  const float* n1_ln_b  = (const float*)d_in[i++];
  const float* n1_w1    = (const float*)d_in[i++];
  const float* n1_b1    = (const float*)d_in[i++];
  const float* n1_w2    = (const float*)d_in[i++];
  const float* n1_b2    = (const float*)d_in[i++];
  const float* tv2_ln_g = (const float*)d_in[i++];
  const float* tv2_ln_b = (const float*)d_in[i++];
  const float* tv2_w    = (const float*)d_in[i++];
  const float* to2_w    = (const float*)d_in[i++];
  const float* to2_b    = (const float*)d_in[i++];
  const float* n2_ln_g  = (const float*)d_in[i++];
  const float* n2_ln_b  = (const float*)d_in[i++];
  const float* n2_w1    = (const float*)d_in[i++];
  const float* n2_b1    = (const float*)d_in[i++];
  const float* n2_w2    = (const float*)d_in[i++];
  const float* n2_b2    = (const float*)d_in[i++];
  const float* brdf_ln_g= (const float*)d_in[i++];
  const float* brdf_ln_b= (const float*)d_in[i++];
  const float* brdf_w1  = (const float*)d_in[i++];
  const float* brdf_b1  = (const float*)d_in[i++];
  const float* brdf_w2  = (const float*)d_in[i++];
  const float* brdf_b2  = (const float*)d_in[i++];

  float* ws = (float*)d_ws;

  mva_phaseA<<<dim3(NBA), dim3(NTA), 0, stream>>>(
      view_dir, normal, DL, pbr_ln_g, pbr_ln_b,
      pbr_w1, pbr_b1, pbr_w2, pbr_b2, pbr_w3, pbr_b3, pbr_w4, pbr_b4, ws);

  mva_phaseB1<<<dim3(NBB1), dim3(NTB), 0, stream>>>(
      rgb, fm, proj_err, ws,
      tv1_ln_g, tv1_ln_b, tv1_w, to1_w, to1_b,
      n1_ln_g, n1_ln_b, n1_w1, n1_b1, n1_w2, n1_b2,
      tv2_ln_g, tv2_ln_b, tv2_w);

  mva_phaseB2<<<dim3(NBB2), dim3(NTB), 0, stream>>>(
      rgb, fm, ws,
      to2_w, to2_b,
      n2_ln_g, n2_ln_b, n2_w1, n2_b1, n2_w2, n2_b2,
      brdf_ln_g, brdf_ln_b, brdf_w1, brdf_b1, brdf_w2, brdf_b2,
      (float*)d_out);
}

// Round 14
// 1086.017 us; speedup vs baseline: 2.4287x; 1.0384x over previous
//
#include <hip/hip_runtime.h>
#include <math.h>

// MultiViewAggregation — round 14.
// A: round-13 (2px row-batched MLP + T14 weight prefetch), unchanged.
// B1/B2: T14 prefetch applied — weights global->reg one mm-phase early,
//        ds_write after the post-mm barrier. Same math, fewer stalls.

#define NPIX 16384

__device__ __forceinline__ float elu_f(float x){ return x > 0.f ? x : (__expf(x) - 1.f); }
__device__ __forceinline__ float gelu_f(float x){ return 0.5f*x*(1.f + erff(x*0.70710678118654752f)); }

__device__ __forceinline__ void fma4(float4& a, float s, const float4 w){
  a.x = fmaf(s, w.x, a.x); a.y = fmaf(s, w.y, a.y);
  a.z = fmaf(s, w.z, a.z); a.w = fmaf(s, w.w, a.w);
}
__device__ __forceinline__ float4 elu4f(float4 a){
  return make_float4(elu_f(a.x), elu_f(a.y), elu_f(a.z), elu_f(a.w));
}

// ===================== Kernel A (round-13, unchanged) =====================
#define NTA 768
#define NBA (NPIX/2)

constexpr int AYA   = 0;
constexpr int AYB   = 13056;
constexpr int AWB   = 26112;
constexpr int AXL   = 30208;
constexpr int ABIAS = 31744;
constexpr int ATOT  = 31968;

template<int K, int SI, bool DOELU>
__device__ __forceinline__ void mmA64(const float* __restrict__ Xin,
                                      const float* __restrict__ WB,
                                      const float* __restrict__ bias,
                                      float* __restrict__ Yout, int t)
{
  const int rq = t >> 4, c4 = t & 15;
  const float* x0 = Xin + (4*rq+0)*SI;
  const float* x1 = Xin + (4*rq+1)*SI;
  const float* x2 = Xin + (4*rq+2)*SI;
  const float* x3 = Xin + (4*rq+3)*SI;
  const float4* __restrict__ W4 = (const float4*)WB;
  const float4 b = ((const float4*)bias)[c4];
  float4 a0=b, a1=b, a2=b, a3=b;
  #pragma unroll
  for (int k2 = 0; k2 < K/2; ++k2){
    const float2 xa = *(const float2*)(x0 + 2*k2);
    const float2 xb = *(const float2*)(x1 + 2*k2);
    const float2 xc = *(const float2*)(x2 + 2*k2);
    const float2 xd = *(const float2*)(x3 + 2*k2);
    const float4 wA = W4[(2*k2)*16 + c4];
    const float4 wB = W4[(2*k2+1)*16 + c4];
    fma4(a0, xa.x, wA); fma4(a0, xa.y, wB);
    fma4(a1, xb.x, wA); fma4(a1, xb.y, wB);
    fma4(a2, xc.x, wA); fma4(a2, xc.y, wB);
    fma4(a3, xd.x, wA); fma4(a3, xd.y, wB);
  }
  if (DOELU){ a0 = elu4f(a0); a1 = elu4f(a1); a2 = elu4f(a2); a3 = elu4f(a3); }
  *(float4*)(Yout + (4*rq+0)*68 + 4*c4) = a0;
  *(float4*)(Yout + (4*rq+1)*68 + 4*c4) = a1;
  *(float4*)(Yout + (4*rq+2)*68 + 4*c4) = a2;
  *(float4*)(Yout + (4*rq+3)*68 + 4*c4) = a3;
}

__device__ __forceinline__ void mmA32(const float* __restrict__ Xin,
                                      const float* __restrict__ WB,
                                      const float* __restrict__ bias,
                                      float* __restrict__ F, int t)
{
  const int rq = t >> 4, c2 = t & 15;
  const float* x0 = Xin + (4*rq+0)*68;
  const float* x1 = Xin + (4*rq+1)*68;
  const float* x2 = Xin + (4*rq+2)*68;
  const float* x3 = Xin + (4*rq+3)*68;
  const float2* __restrict__ W2 = (const float2*)WB;
  const float2 b = ((const float2*)bias)[c2];
  float2 a0=b, a1=b, a2=b, a3=b;
  #pragma unroll
  for (int k2 = 0; k2 < 32; ++k2){
    const float2 xa = *(const float2*)(x0 + 2*k2);
    const float2 xb = *(const float2*)(x1 + 2*k2);
    const float2 xc = *(const float2*)(x2 + 2*k2);
    const float2 xd = *(const float2*)(x3 + 2*k2);
    const float2 wA = W2[(2*k2)*16 + c2];
    const float2 wB = W2[(2*k2+1)*16 + c2];
    a0.x = fmaf(xa.x, wA.x, a0.x); a0.y = fmaf(xa.x, wA.y, a0.y);
    a0.x = fmaf(xa.y, wB.x, a0.x); a0.y = fmaf(xa.y, wB.y, a0.y);
    a1.x = fmaf(xb.x, wA.x, a1.x); a1.y = fmaf(xb.x, wA.y, a1.y);
    a1.x = fmaf(xb.y, wB.x, a1.x); a1.y = fmaf(xb.y, wB.y, a1.y);
    a2.x = fmaf(xc.x, wA.x, a2.x); a2.y = fmaf(xc.x, wA.y, a2.y);
    a2.x = fmaf(xc.y, wB.x, a2.x); a2.y = fmaf(xc.y, wB.y, a2.y);
    a3.x = fmaf(xd.x, wA.x, a3.x); a3.y = fmaf(xd.x, wA.y, a3.y);
    a3.x = fmaf(xd.y, wB.x, a3.x); a3.y = fmaf(xd.y, wB.y, a3.y);
  }
  *(float2*)(F + (4*rq+0)*34 + 2*c2) = a0;
  *(float2*)(F + (4*rq+1)*34 + 2*c2) = a1;
  *(float2*)(F + (4*rq+2)*34 + 2*c2) = a2;
  *(float2*)(F + (4*rq+3)*34 + 2*c2) = a3;
}

__global__ __launch_bounds__(NTA)
void mva_phaseA(const float* __restrict__ view_dir, const float* __restrict__ normal,
                const float* __restrict__ DL,
                const float* __restrict__ ln_g, const float* __restrict__ ln_b,
                const float* __restrict__ w1, const float* __restrict__ b1,
                const float* __restrict__ w2, const float* __restrict__ b2,
                const float* __restrict__ w3, const float* __restrict__ b3,
                const float* __restrict__ w4, const float* __restrict__ b4,
                float* __restrict__ feat)
{
  __shared__ __align__(16) float smem[ATOT];
  const int t = threadIdx.x;
  const int bpx0 = blockIdx.x*2;
  float4* WB4 = (float4*)(smem + AWB);

  {
    const float4* s = (const float4*)w1;
    for (int i = t; i < 128; i += NTA){
      const int k = i >> 4, c4 = i & 15;
      WB4[i] = (k < 7) ? s[k*16 + c4] : make_float4(0.f,0.f,0.f,0.f);
    }
    float4* d = (float4*)(smem+ABIAS);
    if (t >= 256 && t < 272)      d[t-256]      = ((const float4*)b1)[t-256];
    else if (t >= 272 && t < 288) d[16 + t-272] = ((const float4*)b2)[t-272];
    else if (t >= 288 && t < 304) d[32 + t-288] = ((const float4*)b3)[t-288];
    else if (t >= 304 && t < 312) d[48 + t-304] = ((const float4*)b4)[t-304];
  }
  if (t < 192){
    const int pl = t / 96, rr = t - pl*96;
    const int sg = rr >> 3, view = rr & 7;
    const int px = bpx0 + pl;
    const float nm0 = normal[px*3+0], nm1 = normal[px*3+1], nm2 = normal[px*3+2];
    const float* vd = view_dir + (px*8 + view)*3;
    const float vd0 = vd[0], vd1 = vd[1], vd2 = vd[2];
    const float* dl = DL + px*84 + sg*7;
    const float d0=dl[0], d1=dl[1], d2=dl[2], d3=dl[3], d4=dl[4], d5=dl[5], d6=dl[6];

    const float DLdotN = d0*nm0 + d1*nm1 + d2*nm2;
    const float hv     = (d0*vd0 + d1*vd1 + d2*vd2 + 1.f)*0.5f;
    const float fres   = exp2f((-5.55472f*hv - 6.98316f)*hv);
    const float VdotN  = vd0*nm0 + vd1*nm1 + vd2*nm2;

    const float x0 = DLdotN, x1 = d3, x2 = d4, x3 = d5, x4 = d6, x5 = fres, x6 = VdotN;
    const float m  = (x0+x1+x2+x3+x4+x5+x6)*(1.f/7.f);
    float q, var = 0.f;
    q = x0-m; var += q*q; q = x1-m; var += q*q; q = x2-m; var += q*q;
    q = x3-m; var += q*q; q = x4-m; var += q*q; q = x5-m; var += q*q;
    q = x6-m; var += q*q;
    const float rs = rsqrtf(var*(1.f/7.f) + 1e-5f);
    float* xl = smem + AXL + t*8;
    xl[0] = (x0-m)*rs*ln_g[0] + ln_b[0];
    xl[1] = (x1-m)*rs*ln_g[1] + ln_b[1];
    xl[2] = (x2-m)*rs*ln_g[2] + ln_b[2];
    xl[3] = (x3-m)*rs*ln_g[3] + ln_b[3];
    xl[4] = (x4-m)*rs*ln_g[4] + ln_b[4];
    xl[5] = (x5-m)*rs*ln_g[5] + ln_b[5];
    xl[6] = (x6-m)*rs*ln_g[6] + ln_b[6];
    xl[7] = 0.f;
  }
  __syncthreads();

  float4 p0 = ((const float4*)w2)[t];
  float4 p1 = (t < 256) ? ((const float4*)w2)[t + 768] : make_float4(0.f,0.f,0.f,0.f);
  mmA64<8,8,true>(smem+AXL, smem+AWB, smem+ABIAS+0, smem+AYA, t);
  __syncthreads();
  WB4[t] = p0; if (t < 256) WB4[t + 768] = p1;
  __syncthreads();

  p0 = ((const float4*)w3)[t];
  p1 = (t < 256) ? ((const float4*)w3)[t + 768] : make_float4(0.f,0.f,0.f,0.f);
  mmA64<64,68,true>(smem+AYA, smem+AWB, smem+ABIAS+64, smem+AYB, t);
  __syncthreads();
  WB4[t] = p0; if (t < 256) WB4[t + 768] = p1;
  __syncthreads();

  p0 = (t < 512) ? ((const float4*)w4)[t] : make_float4(0.f,0.f,0.f,0.f);
  mmA64<64,68,true>(smem+AYB, smem+AWB, smem+ABIAS+128, smem+AYA, t);
  __syncthreads();
  if (t < 512) WB4[t] = p0;
  __syncthreads();

  mmA32(smem+AYA, smem+AWB, smem+ABIAS+192, smem+AYB, t);
  __syncthreads();

  if (t < 512){
    const int pl = t >> 8, idx = t & 255;
    const int v = idx >> 5, c = idx & 31;
    float s = 0.f;
    #pragma unroll
    for (int sg = 0; sg < 12; ++sg) s += smem[AYB + (pl*96 + sg*8 + v)*34 + c];
    feat[(size_t)(bpx0 + pl)*256 + idx] = s;
  }
}

// ===================== Shared B machinery =====================
#define NTB 512

template<int KK, int CC, int LDWG>
__device__ __forceinline__ void stageW(const float* __restrict__ Wg, int c4off,
                                       float* __restrict__ wbuf, int t)
{
  constexpr int C4 = CC/4;
  constexpr int N4 = KK*C4;
  const float4* __restrict__ s = (const float4*)Wg;
  float4* d = (float4*)wbuf;
  for (int i = t; i < N4; i += NTB){
    const int k = i / C4, c4 = i - k*C4;
    d[i] = s[k*(LDWG/4) + c4off + c4];
  }
}

// T14 prefetch helpers (pf0..pf5 declared in kernel scope)
#define PFSLOT(Wg, KK, CC, LDWG, C4OFF, SLOT, PFV) { \
  const int _i = t + (SLOT)*512; \
  if ((KK)*((CC)/4) > (SLOT)*512 && _i < (KK)*((CC)/4)){ \
    const int _k = _i/((CC)/4), _c = _i - _k*((CC)/4); \
    PFV = ((const float4*)(Wg))[_k*((LDWG)/4) + (C4OFF) + _c]; } }

#define PFLOADG(Wg, KK, CC, LDWG, C4OFF) \
  PFSLOT(Wg,KK,CC,LDWG,C4OFF,0,pf0) PFSLOT(Wg,KK,CC,LDWG,C4OFF,1,pf1) \
  PFSLOT(Wg,KK,CC,LDWG,C4OFF,2,pf2) PFSLOT(Wg,KK,CC,LDWG,C4OFF,3,pf3) \
  PFSLOT(Wg,KK,CC,LDWG,C4OFF,4,pf4) PFSLOT(Wg,KK,CC,LDWG,C4OFF,5,pf5)

#define PFWR(N4, SLOT, PFV) { if ((N4) > (SLOT)*512 && t + (SLOT)*512 < (N4)) WB4[t+(SLOT)*512] = PFV; }
#define PFWRITE(KK, CC) { \
  PFWR((KK)*((CC)/4),0,pf0) PFWR((KK)*((CC)/4),1,pf1) PFWR((KK)*((CC)/4),2,pf2) \
  PFWR((KK)*((CC)/4),3,pf3) PFWR((KK)*((CC)/4),4,pf4) PFWR((KK)*((CC)/4),5,pf5) }

__device__ __forceinline__ void ln32s(const float* __restrict__ in, int Si,
                                      float* __restrict__ out, int So,
                                      const float* __restrict__ g, const float* __restrict__ b,
                                      int t)
{
  if (t < 256){
    const int r = t >> 3, l8 = t & 7;
    const float* row = in + r*Si;
    float vals[12]; int cols[12];
    float s1 = 0.f, s2 = 0.f;
    #pragma unroll
    for (int i = 0; i < 12; ++i){
      int c = l8 + 8*i + 8*(r & 7); if (c >= 96) c -= 96;
      float a = row[c];
      cols[i] = c; vals[i] = a; s1 += a; s2 += a*a;
    }
    s1 += __shfl_xor(s1, 1); s2 += __shfl_xor(s2, 1);
    s1 += __shfl_xor(s1, 2); s2 += __shfl_xor(s2, 2);
    s1 += __shfl_xor(s1, 4); s2 += __shfl_xor(s2, 4);
    float mean = s1*(1.f/96.f);
    float var  = s2*(1.f/96.f) - mean*mean;
    float rsd = rsqrtf(var + 1e-5f);
    float* orow = out + r*So;
    #pragma unroll
    for (int i = 0; i < 12; ++i){
      int c = cols[i];
      orow[c] = (vals[i]-mean)*rsd*g[c] + b[c];
    }
  }
}

template<int K, int C, int LDW, bool GELU, bool HASB, bool RES, bool ACC>
__device__ __forceinline__ void mmR32(const float* __restrict__ inb, int S,
                                      const float* __restrict__ Wl, const float* __restrict__ bg,
                                      float* __restrict__ outb, int So,
                                      const float* __restrict__ residb, int Sr, int t)
{
  constexpr int C4 = C/4;
  const float4* __restrict__ W4 = (const float4*)Wl;
  for (int gi = t; gi < C4*16; gi += NTB){
    const int rp = gi & 15, c4 = gi >> 4;
    const float2* x0 = (const float2*)(inb + (2*rp)*S);
    const float2* x1 = (const float2*)(inb + (2*rp+1)*S);
    float4 a0 = HASB ? ((const float4*)bg)[c4] : make_float4(0.f,0.f,0.f,0.f);
    float4 a1 = a0;
    #pragma unroll 8
    for (int k2 = 0; k2 < K/2; ++k2){
      float2 xa = x0[k2], xb = x1[k2];
      float4 wA = W4[(2*k2)*(LDW/4) + c4];
      float4 wB = W4[(2*k2+1)*(LDW/4) + c4];
      fma4(a0, xa.x, wA); fma4(a0, xa.y, wB);
      fma4(a1, xb.x, wA); fma4(a1, xb.y, wB);
    }
    if (GELU){
      a0.x=gelu_f(a0.x); a0.y=gelu_f(a0.y); a0.z=gelu_f(a0.z); a0.w=gelu_f(a0.w);
      a1.x=gelu_f(a1.x); a1.y=gelu_f(a1.y); a1.z=gelu_f(a1.z); a1.w=gelu_f(a1.w);
    }
    if (RES){
      const float* r0 = residb + (2*rp)*Sr + 4*c4;
      const float* r1 = residb + (2*rp+1)*Sr + 4*c4;
      a0.x += r0[0]; a0.y += r0[1]; a0.z += r0[2]; a0.w += r0[3];
      a1.x += r1[0]; a1.y += r1[1]; a1.z += r1[2]; a1.w += r1[3];
    }
    float* o0 = outb + (2*rp)*So + 4*c4;
    float* o1 = outb + (2*rp+1)*So + 4*c4;
    if (ACC){
      a0.x += o0[0]; a0.y += o0[1]; a0.z += o0[2]; a0.w += o0[3];
      a1.x += o1[0]; a1.y += o1[1]; a1.z += o1[2]; a1.w += o1[3];
    }
    o0[0]=a0.x; o0[1]=a0.y; o0[2]=a0.z; o0[3]=a0.w;
    o1[0]=a1.x; o1[1]=a1.y; o1[2]=a1.z; o1[3]=a1.w;
  }
}

// ===================== Kernel B1 (T14 prefetch) =====================
#define NBB1 (NPIX/4)
constexpr int BXIN  = 0;
constexpr int BXCUR = 3264;
constexpr int BXLN  = 6528;
constexpr int BHID  = 9792;
constexpr int BVB   = 14080;
constexpr int BMEAN = 15296;
constexpr int BVAR  = 15424;
constexpr int BWGT  = 15552;
constexpr int BWBUF = 15584;
constexpr int B1TOT = 27872;

__global__ __launch_bounds__(NTB)
void mva_phaseB1(const float* __restrict__ rgb, const float* __restrict__ fm,
                 const float* __restrict__ proj_err, float* __restrict__ ws,
                 const float* __restrict__ tv1_ln_g, const float* __restrict__ tv1_ln_b,
                 const float* __restrict__ tv1_w,
                 const float* __restrict__ to1_w, const float* __restrict__ to1_b,
                 const float* __restrict__ n1_ln_g, const float* __restrict__ n1_ln_b,
                 const float* __restrict__ n1_w1, const float* __restrict__ n1_b1,
                 const float* __restrict__ n1_w2, const float* __restrict__ n1_b2,
                 const float* __restrict__ tv2_ln_g, const float* __restrict__ tv2_ln_b,
                 const float* __restrict__ tv2_w)
{
  __shared__ __align__(16) float smem[B1TOT];
  const int t = threadIdx.x;
  const int bpx0 = blockIdx.x*4;
  float* WB = smem + BWBUF;
  float4* WB4 = (float4*)WB;
  float4 pf0 = make_float4(0,0,0,0), pf1 = pf0, pf2 = pf0, pf3 = pf0, pf4 = pf0, pf5 = pf0;

  // A: xin + wgt + stage tv1
  for (int u = t; u < 2048; u += NTB){
    const int r = u >> 6, k = u & 63;
    const int pl = r >> 3, v = r & 7;
    float val = (k < 3) ? rgb[((bpx0+pl)*8 + v)*3 + k]
                        : fm[(bpx0+pl)*61 + (k-3)];
    smem[BXIN + r*102 + k] = val;
  }
  for (int u = t; u < 1024; u += NTB){
    const int r = u >> 5, c = u & 31;
    smem[BXIN + r*102 + 64 + c] = ws[(size_t)blockIdx.x*1024 + u];
  }
  if (t < 32){
    float pe = proj_err[(bpx0 + (t>>3))*8 + (t&7)];
    float wraw = fmaxf(-log10f(fabsf(pe) + 1e-6f), 0.f);
    float s = wraw;
    s += __shfl_xor(s, 1); s += __shfl_xor(s, 2); s += __shfl_xor(s, 4);
    smem[BWGT + t] = wraw / (s + 1e-6f);
  }
  stageW<96,32,32>(tv1_w, 0, WB, t);
  __syncthreads();

  // B: ln ; prefetch to1
  ln32s(smem+BXIN, 102, smem+BXLN, 102, tv1_ln_g, tv1_ln_b, t);
  PFLOADG(to1_w, 96,96,96, 0)
  __syncthreads();
  // C: mm tv1
  mmR32<96,32,32,false,false,false,false>(smem+BXLN, 102, WB, nullptr, smem+BVB, 38, nullptr, 0, t);
  __syncthreads();
  // D: stats + write to1
  if (t < 128){
    const int pl = t >> 5, c = t & 31;
    const float* wn = smem + BWGT + pl*8;
    float m = 0.f;
    #pragma unroll
    for (int v = 0; v < 8; ++v) m += wn[v]*smem[BVB + (pl*8+v)*38 + c];
    float vv = 0.f;
    #pragma unroll
    for (int v = 0; v < 8; ++v){ float d = smem[BVB + (pl*8+v)*38 + c] - m; vv += wn[v]*d*d; }
    smem[BMEAN + pl*32 + c] = m;
    smem[BVAR  + pl*32 + c] = vv;
  }
  PFWRITE(96,96)
  __syncthreads();
  // E: xcat -> XLN
  for (int u = t; u < 3072; u += NTB){
    const int r = u & 31, c = u >> 5;
    const int pl = r >> 3;
    float val = (c < 32) ? smem[BVB + r*38 + c]
              : (c < 64) ? smem[BMEAN + pl*32 + (c-32)]
                         : smem[BVAR + pl*32 + (c-64)];
    smem[BXLN + r*102 + c] = val;
  }
  __syncthreads();
  // F: mm to1 ; prefetch n1w1a
  PFLOADG(n1_w1, 96,128,256, 0)
  mmR32<96,96,96,false,true,true,false>(smem+BXLN, 102, WB, to1_b, smem+BXCUR, 102, smem+BXIN, 102, t);
  __syncthreads();
  // G: ln + write n1w1a
  ln32s(smem+BXCUR, 102, smem+BXLN, 102, n1_ln_g, n1_ln_b, t);
  PFWRITE(96,128)
  __syncthreads();
  // H: mm n1w1a ; prefetch n1w2a
  PFLOADG(n1_w2, 128,96,96, 0)
  mmR32<96,128,128,true,true,false,false>(smem+BXLN, 102, WB, n1_b1, smem+BHID, 134, nullptr, 0, t);
  __syncthreads();
  // I: write n1w2a
  PFWRITE(128,96)
  __syncthreads();
  // J: mm n1w2a ; prefetch n1w1b
  PFLOADG(n1_w1, 96,128,256, 32)
  mmR32<128,96,96,false,false,false,false>(smem+BHID, 134, WB, nullptr, smem+BXCUR, 102, nullptr, 0, t);
  __syncthreads();
  // K: write n1w1b
  PFWRITE(96,128)
  __syncthreads();
  // L: mm n1w1b ; prefetch n1w2b
  PFLOADG(n1_w2 + 128*96, 128,96,96, 0)
  mmR32<96,128,128,true,true,false,false>(smem+BXLN, 102, WB, n1_b1 + 128, smem+BHID, 134, nullptr, 0, t);
  __syncthreads();
  // M: write n1w2b
  PFWRITE(128,96)
  __syncthreads();
  // N: mm n1w2b (resid+ACC) ; prefetch tv2
  PFLOADG(tv2_w, 96,32,32, 0)
  mmR32<128,96,96,false,true,true,true>(smem+BHID, 134, WB, n1_b2, smem+BXCUR, 102, smem+BXIN, 102, t);
  __syncthreads();
  // O: ln tv2 + write tv2
  ln32s(smem+BXCUR, 102, smem+BXLN, 102, tv2_ln_g, tv2_ln_b, t);
  PFWRITE(96,32)
  __syncthreads();
  // P: mm tv2
  mmR32<96,32,32,false,false,false,false>(smem+BXLN, 102, WB, nullptr, smem+BVB, 38, nullptr, 0, t);
  __syncthreads();
  // Q: stats
  if (t < 128){
    const int pl = t >> 5, c = t & 31;
    const float* wn = smem + BWGT + pl*8;
    float m = 0.f;
    #pragma unroll
    for (int v = 0; v < 8; ++v) m += wn[v]*smem[BVB + (pl*8+v)*38 + c];
    float vv = 0.f;
    #pragma unroll
    for (int v = 0; v < 8; ++v){ float d = smem[BVB + (pl*8+v)*38 + c] - m; vv += wn[v]*d*d; }
    smem[BMEAN + pl*32 + c] = m;
    smem[BVAR  + pl*32 + c] = vv;
  }
  __syncthreads();
  // R: xcat2 -> ws
  if (t < 384){
    const int pl = t / 96, c = t - pl*96;
    float val = (c < 32) ? smem[BVB + (pl*8)*38 + c]
              : (c < 64) ? smem[BMEAN + pl*32 + (c-32)]
                         : smem[BVAR + pl*32 + (c-64)];
    ws[(size_t)blockIdx.x*1024 + pl*256 + 96 + c] = val;
  }
}

// ===================== Kernel B2 (T14 prefetch) =====================
#define NBB2 (NPIX/32)
constexpr int CXLN  = 0;
constexpr int CXIN  = 3264;
constexpr int CXS   = 6528;
constexpr int CTMP  = 9792;
constexpr int CHID  = 13056;
constexpr int CWBUF = 17344;
constexpr int B2TOT = 29632;

__global__ __launch_bounds__(NTB)
void mva_phaseB2(const float* __restrict__ rgb, const float* __restrict__ fm,
                 const float* __restrict__ ws,
                 const float* __restrict__ to2_w, const float* __restrict__ to2_b,
                 const float* __restrict__ n2_ln_g, const float* __restrict__ n2_ln_b,
                 const float* __restrict__ n2_w1, const float* __restrict__ n2_b1,
                 const float* __restrict__ n2_w2, const float* __restrict__ n2_b2,
                 const float* __restrict__ brdf_ln_g, const float* __restrict__ brdf_ln_b,
                 const float* __restrict__ brdf_w1, const float* __restrict__ brdf_b1,
                 const float* __restrict__ brdf_w2, const float* __restrict__ brdf_b2,
                 float* __restrict__ out)
{
  __shared__ __align__(16) float smem[B2TOT];
  const int t = threadIdx.x;
  const int bpx0 = blockIdx.x*32;
  float* WB = smem + CWBUF;
  float4* WB4 = (float4*)WB;
  float4 pf0 = make_float4(0,0,0,0), pf1 = pf0, pf2 = pf0, pf3 = pf0, pf4 = pf0, pf5 = pf0;

  // A: loads + stage to2
  for (int u = t; u < 3072; u += NTB){
    const int r = u / 96, c = u - r*96;
    const int px = bpx0 + r;
    const size_t ab = (size_t)px*256;
    smem[CXLN + r*102 + c] = ws[ab + 96 + c];
    float xv = (c < 3)  ? rgb[((size_t)px*8)*3 + c]
             : (c < 64) ? fm[(size_t)px*61 + (c-3)]
                        : ws[ab + (c-64)];
    smem[CXIN + r*102 + c] = xv;
  }
  stageW<96,96,96>(to2_w, 0, WB, t);
  __syncthreads();

  // B: mm to2 ; prefetch n2w1a
  PFLOADG(n2_w1, 96,128,256, 0)
  mmR32<96,96,96,false,true,true,false>(smem+CXLN, 102, WB, to2_b, smem+CXS, 102, smem+CXIN, 102, t);
  __syncthreads();
  // C: ln + write n2w1a
  ln32s(smem+CXS, 102, smem+CXLN, 102, n2_ln_g, n2_ln_b, t);
  PFWRITE(96,128)
  __syncthreads();
  // D: mm n2w1a ; prefetch n2w2a
  PFLOADG(n2_w2, 128,96,96, 0)
  mmR32<96,128,128,true,true,false,false>(smem+CXLN, 102, WB, n2_b1, smem+CHID, 134, nullptr, 0, t);
  __syncthreads();
  // E: write
  PFWRITE(128,96)
  __syncthreads();
  // F: mm n2w2a ; prefetch n2w1b
  PFLOADG(n2_w1, 96,128,256, 32)
  mmR32<128,96,96,false,false,false,false>(smem+CHID, 134, WB, nullptr, smem+CTMP, 102, nullptr, 0, t);
  __syncthreads();
  // G: write
  PFWRITE(96,128)
  __syncthreads();
  // H: mm n2w1b ; prefetch n2w2b
  PFLOADG(n2_w2 + 128*96, 128,96,96, 0)
  mmR32<96,128,128,true,true,false,false>(smem+CXLN, 102, WB, n2_b1 + 128, smem+CHID, 134, nullptr, 0, t);
  __syncthreads();
  // I: write
  PFWRITE(128,96)
  __syncthreads();
  // J: mm n2w2b (resid+ACC) ; prefetch brdf_w1
  PFLOADG(brdf_w1, 96,128,128, 0)
  mmR32<128,96,96,false,true,true,true>(smem+CHID, 134, WB, n2_b2, smem+CTMP, 102, smem+CXIN, 102, t);
  __syncthreads();
  // K: ln brdf + write brdf_w1
  ln32s(smem+CTMP, 102, smem+CXLN, 102, brdf_ln_g, brdf_ln_b, t);
  PFWRITE(96,128)
  __syncthreads();
  // L: mm brdf_w1 ; prefetch brdf_w2a
  PFLOADG(brdf_w2, 128,64,128, 0)
  mmR32<96,128,128,true,true,false,false>(smem+CXLN, 102, WB, brdf_b1, smem+CHID, 134, nullptr, 0, t);
  __syncthreads();
  // M: write
  PFWRITE(128,64)
  __syncthreads();
  // N: mm brdf_w2a -> out lo ; prefetch brdf_w2b
  float* outp = out + (size_t)bpx0*128;
  PFLOADG(brdf_w2, 128,64,128, 16)
  mmR32<128,64,64,false,true,false,false>(smem+CHID, 134, WB, brdf_b2, outp, 128, nullptr, 0, t);
  __syncthreads();
  // O: write
  PFWRITE(128,64)
  __syncthreads();
  // P: mm brdf_w2b -> out hi
  mmR32<128,64,64,false,true,false,false>(smem+CHID, 134, WB, brdf_b2 + 64, outp + 64, 128, nullptr, 0, t);
}

extern "C" void kernel_launch(void* const* d_in, const int* in_sizes, int n_in,
                              void* d_out, int out_size, void* d_ws, size_t ws_size,
                              hipStream_t stream)
{
  (void)in_sizes; (void)n_in; (void)ws_size; (void)out_size;
  int i = 0;
  const float* rgb      = (const float*)d_in[i++];
  const float* fm       = (const float*)d_in[i++];
  const float* view_dir = (const float*)d_in[i++];
  const float* proj_err = (const float*)d_in[i++];
  const float* normal   = (const float*)d_in[i++];
  const float* DL       = (const float*)d_in[i++];
  const float* pbr_ln_g = (const float*)d_in[i++];
  const float* pbr_ln_b = (const float*)d_in[i++];
  const float* pbr_w1   = (const float*)d_in[i++];
  const float* pbr_b1   = (const float*)d_in[i++];
  const float* pbr_w2   = (const float*)d_in[i++];
  const float* pbr_b2   = (const float*)d_in[i++];
  const float* pbr_w3   = (const float*)d_in[i++];
  const float* pbr_b3   = (const float*)d_in[i++];
  const float* pbr_w4   = (const float*)d_in[i++];
  const float* pbr_b4   = (const float*)d_in[i++];
  const float* tv1_ln_g = (const float*)d_in[i++];
  const float* tv1_ln_b = (const float*)d_in[i++];
  const float* tv1_w    = (const float*)d_in[i++];
  const float* to1_w    = (const float*)d_in[i++];
  const float* to1_b    = (const float*)d_in[i++];
  const float* n1_ln_g  = (const float*)d_in[i++];
  const float* n1_ln_b  = (const float*)d_in[i++];
  const float* n1_w1    = (const float*)d_in[i++];
  const float* n1_b1    = (const float*)d_in[i++];
  const float* n1_w2    = (const float*)d_in[i++];
  const float* n1_b2    = (const float*)d_in[i++];
  const float* tv2_ln_g = (const float*)d_in[i++];
  const float* tv2_ln_b = (const float*)d_in[i++];
  const float* tv2_w    = (const float*)d_in[i++];
  const float* to2_w    = (const float*)d_in[i++];
  const float* to2_b    = (const float*)d_in[i++];
  const float* n2_ln_g  = (const float*)d_in[i++];
  const float* n2_ln_b  = (const float*)d_in[i++];
  const float* n2_w1    = (const float*)d_in[i++];
  const float* n2_b1    = (const float*)d_in[i++];
  const float* n2_w2    = (const float*)d_in[i++];
  const float* n2_b2    = (const float*)d_in[i++];
  const float* brdf_ln_g= (const float*)d_in[i++];
  const float* brdf_ln_b= (const float*)d_in[i++];
  const float* brdf_w1  = (const float*)d_in[i++];
  const float* brdf_b1  = (const float*)d_in[i++];
  const float* brdf_w2  = (const float*)d_in[i++];
  const float* brdf_b2  = (const float*)d_in[i++];

  float* ws = (float*)d_ws;

  mva_phaseA<<<dim3(NBA), dim3(NTA), 0, stream>>>(
      view_dir, normal, DL, pbr_ln_g, pbr_ln_b,
      pbr_w1, pbr_b1, pbr_w2, pbr_b2, pbr_w3, pbr_b3, pbr_w4, pbr_b4, ws);

  mva_phaseB1<<<dim3(NBB1), dim3(NTB), 0, stream>>>(
      rgb, fm, proj_err, ws,
      tv1_ln_g, tv1_ln_b, tv1_w, to1_w, to1_b,
      n1_ln_g, n1_ln_b, n1_w1, n1_b1, n1_w2, n1_b2,
      tv2_ln_g, tv2_ln_b, tv2_w);

  mva_phaseB2<<<dim3(NBB2), dim3(NTB), 0, stream>>>(
      rgb, fm, ws,
      to2_w, to2_b,
      n2_ln_g, n2_ln_b, n2_w1, n2_b1, n2_w2, n2_b2,
      brdf_ln_g, brdf_ln_b, brdf_w1, brdf_b1, brdf_w2, brdf_b2,
      (float*)d_out);
}